// Round 9
// baseline (618.644 us; speedup 1.0000x reference)
//
#include <hip/hip_runtime.h>
#include <hip/hip_fp16.h>

// N=100000 nodes, E=1000000 edges, D_IN=16, H=2, C=64.
// 3x (GAT -> BN -> ReLU), then MLP head -> (logits, value) concat in d_out.
// R27: (a) degree-rank perm — bucket_sort counting-sorts each 256-node chunk
// by degree (32 bins, LDS); aggregate processes nodes in perm order so the 4
// node-groups of a wave have near-equal degree (kills the max-of-4-Poisson
// divergence tax, ~30% of the edge loop). Numerically exact. (b) bn_finalize
// fused into bn_stats via last-block pattern (threadfence+counter; 256
// atomics on ONE address — not R19's 3.2M storm). Kept: R26 MFMA fp16
// projection (matrix pipe), R24 aggregate shape (4-deep, 16 lanes/node),
// NT out stores, R17 CSR build, scsh BN fusion into consumers.

__device__ __forceinline__ float leaky(float x) { return x > 0.f ? x : 0.2f * x; }

typedef float f32x4 __attribute__((ext_vector_type(4)));
typedef _Float16 f16x8 __attribute__((ext_vector_type(8)));

#define BCAP 4096  // max edges per 256-dst bucket (mean ~2560)
#define NSL 256    // bn_stats slices

// ---------------- CSR build ----------------
__global__ void bucket_hist(const int* __restrict__ dst, int* __restrict__ bcnt, int E) {
  __shared__ int cnt[512];
  int t = threadIdx.x;
  cnt[t] = 0; cnt[t + 256] = 0;
  __syncthreads();
  for (int e = blockIdx.x * blockDim.x + t; e < E; e += gridDim.x * blockDim.x)
    atomicAdd(&cnt[dst[e] >> 8], 1);
  __syncthreads();
  for (int i = t; i < 512; i += 256)
    if (cnt[i]) atomicAdd(&bcnt[i], cnt[i]);
}

__global__ void bucket_scan(const int* __restrict__ bcnt, int* __restrict__ boff,
                            int* __restrict__ bcur, int nbk) {
  __shared__ int temp[512];
  int t = threadIdx.x;  // 512 threads
  int v = (t < nbk) ? bcnt[t] : 0;
  temp[t] = v;
  __syncthreads();
  for (int off = 1; off < 512; off <<= 1) {
    int add = (t >= off) ? temp[t - off] : 0;
    __syncthreads();
    temp[t] += add;
    __syncthreads();
  }
  if (t < nbk) {
    int ex = temp[t] - v;
    boff[t] = ex;
    bcur[t] = ex;
  }
}

__global__ __launch_bounds__(256) void bin_scatter(
    const int* __restrict__ src, const int* __restrict__ dst,
    int* __restrict__ bcur, int2* __restrict__ ebuf, int E) {
  __shared__ int cnt[512];
  __shared__ int base[512];
  int t = threadIdx.x;
  int beg = blockIdx.x * 8192;
  int end = min(E, beg + 8192);
  cnt[t] = 0; cnt[t + 256] = 0;
  __syncthreads();
  for (int e = beg + t; e < end; e += 256)
    atomicAdd(&cnt[dst[e] >> 8], 1);
  __syncthreads();
  for (int i = t; i < 512; i += 256) {
    base[i] = cnt[i] ? atomicAdd(&bcur[i], cnt[i]) : 0;
    cnt[i] = 0;  // reuse as within-run cursor
  }
  __syncthreads();
  for (int e = beg + t; e < end; e += 256) {
    int d = dst[e];
    int bk = d >> 8;
    int off = atomicAdd(&cnt[bk], 1);
    ebuf[base[bk] + off] = make_int2(src[e], d);
  }
}

__global__ __launch_bounds__(256) void bucket_sort(
    const int2* __restrict__ ebuf, const int* __restrict__ boff,
    int* __restrict__ col, int* __restrict__ row_ptr, int* __restrict__ perm,
    int E, int n, int nbk) {
  __shared__ int2 eds[BCAP];
  __shared__ int dcnt[256];
  __shared__ int dbase[256];
  __shared__ int dexcl[256];
  __shared__ int dgh[32];
  int b = blockIdx.x, t = threadIdx.x;
  int S = boff[b];
  int Eend = (b + 1 < nbk) ? boff[b + 1] : E;
  int cnt = min(Eend - S, BCAP);
  for (int i = t; i < cnt; i += 256) eds[i] = ebuf[S + i];
  dcnt[t] = 0;
  if (t < 32) dgh[t] = 0;
  perm[(b << 8) + t] = n;  // sentinel fill (overwritten for valid ranks)
  __syncthreads();
  for (int i = t; i < cnt; i += 256) atomicAdd(&dcnt[eds[i].y & 255], 1);
  __syncthreads();
  int v = dcnt[t];
  dbase[t] = v;
  __syncthreads();
  for (int off = 1; off < 256; off <<= 1) {
    int add = (t >= off) ? dbase[t - off] : 0;
    __syncthreads();
    dbase[t] += add;
    __syncthreads();
  }
  int excl = dbase[t] - v;
  int d = (b << 8) + t;
  bool valid = (d < n);
  if (valid) row_ptr[d] = S + excl;
  if (b == nbk - 1 && t == 0) row_ptr[n] = E;
  // ---- degree-rank perm: counting sort of this chunk's nodes by degree
  int bin = min(v, 31);
  int within = 0;
  if (valid) within = atomicAdd(&dgh[bin], 1);
  __syncthreads();
  if (t == 0) {
    int s = 0;
    for (int i = 0; i < 32; i++) { int c = dgh[i]; dgh[i] = s; s += c; }
  }
  __syncthreads();
  if (valid) perm[(b << 8) + dgh[bin] + within] = d;
  // ---- edge scatter into sorted CSR
  dcnt[t] = 0;  // reuse as per-dst cursor
  dexcl[t] = excl;
  __syncthreads();
  for (int i = t; i < cnt; i += 256) {
    int2 e = eds[i];
    int dl = e.y & 255;
    int off = atomicAdd(&dcnt[dl], 1);
    col[S + dexcl[dl] + off] = e.x;
  }
}

// ---------------- BN stats (slice writes) + fused last-block finalize -------
__global__ __launch_bounds__(256) void bn_stats(
    const float* __restrict__ h, float* __restrict__ stats,
    const float* __restrict__ g, const float* __restrict__ be,
    float* __restrict__ scsh, int* __restrict__ ctr, float inv_n, int n) {
  __shared__ float ssum[64], ssq[64];
  __shared__ float red2[256];
  __shared__ int lastf;
  int t = threadIdx.x;
  if (t < 64) { ssum[t] = 0.f; ssq[t] = 0.f; }
  __syncthreads();
  const float4* h4 = (const float4*)h;
  size_t total4 = (size_t)n * 16;
  size_t stride = (size_t)gridDim.x * blockDim.x;   // multiple of 16
  int cbase = ((int)(((size_t)blockIdx.x * blockDim.x + t) & 15)) * 4;
  float s0 = 0.f, s1 = 0.f, s2 = 0.f, s3 = 0.f;
  float q0 = 0.f, q1 = 0.f, q2 = 0.f, q3 = 0.f;
  for (size_t i = (size_t)blockIdx.x * blockDim.x + t; i < total4; i += stride) {
    float4 v = h4[i];
    s0 += v.x; q0 = fmaf(v.x, v.x, q0);
    s1 += v.y; q1 = fmaf(v.y, v.y, q1);
    s2 += v.z; q2 = fmaf(v.z, v.z, q2);
    s3 += v.w; q3 = fmaf(v.w, v.w, q3);
  }
  atomicAdd(&ssum[cbase + 0], s0); atomicAdd(&ssq[cbase + 0], q0);
  atomicAdd(&ssum[cbase + 1], s1); atomicAdd(&ssq[cbase + 1], q1);
  atomicAdd(&ssum[cbase + 2], s2); atomicAdd(&ssq[cbase + 2], q2);
  atomicAdd(&ssum[cbase + 3], s3); atomicAdd(&ssq[cbase + 3], q3);
  __syncthreads();
  if (t < 64) {
    stats[blockIdx.x * 128 + t] = ssum[t];
    stats[blockIdx.x * 128 + 64 + t] = ssq[t];
  }
  // ---- last-block finalize (release: fence-all, then counter)
  __threadfence();
  __syncthreads();
  if (t == 0) {
    int old = atomicAdd(ctr, 1);
    lastf = (old == NSL - 1) ? 1 : 0;
  }
  __syncthreads();
  if (!lastf) return;
  if (t == 0) *ctr = 0;  // reset for next layer (stream-ordered)
  __threadfence();       // acquire: see all blocks' slice writes
  int c = t & 127, half = t >> 7;
  float acc = 0.f;
  for (int bsl = half * 128; bsl < half * 128 + 128; bsl++)
    acc += stats[bsl * 128 + c];
  red2[t] = acc;
  __syncthreads();
  if (t < 64) {
    float s  = red2[t] + red2[t + 128];
    float sq = red2[64 + t] + red2[64 + t + 128];
    float mean = s * inv_n;
    float var = sq * inv_n - mean * mean;
    float sc = rsqrtf(var + 1e-5f) * g[t];
    scsh[t] = sc;
    scsh[64 + t] = be[t] - mean * sc;
  }
}

// ---------------- GAT projection: MFMA fp16, 64 nodes x 128 cols ------------
// h = act @ W on the matrix pipe. 4 waves; wave w owns node rows w*16..+15,
// all 8 col-tiles. A[64][KP] and W^T[128][KP] staged fp16 in LDS, KP = KE+8
// (odd 16B stride -> conflict-free ds_read_b128 fragments). K=16 zero-padded
// to KE=32. C/D layout (m89): col=lane&15, row=(lane>>4)*4+reg.
template <int K, bool BN>
__global__ __launch_bounds__(256) void gat_project_mfma(
    const float* __restrict__ act, const float* __restrict__ scsh,
    const float* __restrict__ W,
    const float* __restrict__ att_s, const float* __restrict__ att_d,
    __half2* __restrict__ hb, float* __restrict__ as_,
    float* __restrict__ ad_, int n) {
  constexpr int KE = (K < 32) ? 32 : K;   // effective (padded) K
  constexpr int KP = KE + 8;              // LDS stride in halves
  constexpr int STAGE = 64 * KP * 2 + 128 * KP * 2;
  constexpr int HSZ = 64 * 136 * 2;
  constexpr int LDSZ = (STAGE > HSZ) ? STAGE : HSZ;
  __shared__ __align__(16) char ldsb[LDSZ];
  __shared__ float attS[256];
  __half* aH = (__half*)ldsb;                      // [64][KP]
  __half* wT = (__half*)(ldsb + 64 * KP * 2);      // [128][KP] (transposed W)
  __half* hS = (__half*)ldsb;                      // [64][136], aliases after barrier

  int t = threadIdx.x;
  int node0 = blockIdx.x * 64;
  int rows = min(64, n - node0);

  // ---- stage A: fp32 -> fp16, BN+ReLU fused; zero-pad r>=rows and k>=K
  constexpr int ACH = 64 * KE / 4;
  for (int i = t; i < ACH; i += 256) {
    int r = i / (KE / 4), kc = i % (KE / 4);
    float4 v = make_float4(0.f, 0.f, 0.f, 0.f);
    if (r < rows && kc * 4 < K)
      v = *(const float4*)&act[(size_t)(node0 + r) * K + kc * 4];
    if (BN) {
      float4 sc4 = *(const float4*)&scsh[kc * 4];
      float4 sh4 = *(const float4*)&scsh[64 + kc * 4];
      v.x = fmaxf(fmaf(v.x, sc4.x, sh4.x), 0.f);
      v.y = fmaxf(fmaf(v.y, sc4.y, sh4.y), 0.f);
      v.z = fmaxf(fmaf(v.z, sc4.z, sh4.z), 0.f);
      v.w = fmaxf(fmaf(v.w, sc4.w, sh4.w), 0.f);
    }
    __half2 h01 = __floats2half2_rn(v.x, v.y);
    __half2 h23 = __floats2half2_rn(v.z, v.w);
    uint2 pk = make_uint2(__builtin_bit_cast(unsigned, h01),
                          __builtin_bit_cast(unsigned, h23));
    *(uint2*)&aH[r * KP + kc * 4] = pk;
  }
  // ---- stage W^T: wT[c][k] fp16 (coalesced global read)
  for (int i = t; i < KE * 128; i += 256) {
    int k = i >> 7, c = i & 127;
    float wv = (k < K) ? W[k * 128 + c] : 0.f;
    wT[c * KP + k] = __float2half(wv);
  }
  attS[t] = (t < 128) ? att_s[t] : att_d[t - 128];
  __syncthreads();

  int w = t >> 6, l = t & 63;
  int cl = l & 15, r4 = l >> 4;
  int w16 = w * 16;

  f32x4 acc[8] = {};
#pragma unroll
  for (int ks = 0; ks < KE / 32; ks++) {
    f16x8 av = *(const f16x8*)&aH[(w16 + cl) * KP + ks * 32 + r4 * 8];
#pragma unroll
    for (int ct = 0; ct < 8; ct++) {
      f16x8 bv = *(const f16x8*)&wT[(ct * 16 + cl) * KP + ks * 32 + r4 * 8];
      acc[ct] = __builtin_amdgcn_mfma_f32_16x16x32_f16(av, bv, acc[ct], 0, 0, 0);
    }
  }

  // ---- att scores from accumulators (per-row dot with att vectors)
  float ats[8], atd[8];
#pragma unroll
  for (int ct = 0; ct < 8; ct++) {
    ats[ct] = attS[ct * 16 + cl];
    atd[ct] = attS[128 + ct * 16 + cl];
  }
#pragma unroll
  for (int i = 0; i < 4; i++) {
    float s0 = 0.f, s1 = 0.f, d0 = 0.f, d1 = 0.f;
#pragma unroll
    for (int ct = 0; ct < 4; ct++) {
      s0 = fmaf(acc[ct][i], ats[ct], s0);
      d0 = fmaf(acc[ct][i], atd[ct], d0);
      s1 = fmaf(acc[ct + 4][i], ats[ct + 4], s1);
      d1 = fmaf(acc[ct + 4][i], atd[ct + 4], d1);
    }
#pragma unroll
    for (int off = 1; off < 16; off <<= 1) {
      s0 += __shfl_xor(s0, off); s1 += __shfl_xor(s1, off);
      d0 += __shfl_xor(d0, off); d1 += __shfl_xor(d1, off);
    }
    int rloc = w16 + r4 * 4 + i;
    if (rloc < rows) {
      int row = node0 + rloc;
      if (cl == 0) as_[row * 2] = s0;
      else if (cl == 1) as_[row * 2 + 1] = s1;
      else if (cl == 2) ad_[row * 2] = d0;
      else if (cl == 3) ad_[row * 2 + 1] = d1;
    }
  }

  __syncthreads();  // aH/wT dead -> reuse as hS
  // ---- C fragments -> hS fp16 [64][136]
#pragma unroll
  for (int ct = 0; ct < 8; ct++)
#pragma unroll
    for (int i = 0; i < 4; i++)
      hS[(w16 + r4 * 4 + i) * 136 + ct * 16 + cl] = __float2half(acc[ct][i]);
  __syncthreads();
  // ---- hS -> hb, coalesced 16B chunks (256B per node row)
#pragma unroll
  for (int it = 0; it < 4; it++) {
    int flat = t + it * 256;
    int nd = flat >> 4, ch = flat & 15;
    if (nd < rows)
      *(uint4*)((char*)hb + (((size_t)(node0 + nd)) << 8) + (ch << 4)) =
          *(const uint4*)((const char*)hS + nd * 272 + (ch << 4));
  }
}

// ---------------- GAT aggregation: 16 lanes/node, 4 nodes/wave (R24) --------
// Nodes visited in degree-rank perm order -> the 4 groups of a wave have
// near-equal degree (no max-of-4 divergence tax). Lane q accumulates its 8
// channels of head (q>=8) over ALL edges; 4-deep unroll; redundant per-lane
// den; 9-op head-swap epilogue; NT out stores.
__device__ __forceinline__ void fma8(float* a, float my, uint4 raw) {
  float2 f;
  f = __half22float2(__builtin_bit_cast(__half2, raw.x)); a[0] = fmaf(my, f.x, a[0]); a[1] = fmaf(my, f.y, a[1]);
  f = __half22float2(__builtin_bit_cast(__half2, raw.y)); a[2] = fmaf(my, f.x, a[2]); a[3] = fmaf(my, f.y, a[3]);
  f = __half22float2(__builtin_bit_cast(__half2, raw.z)); a[4] = fmaf(my, f.x, a[4]); a[5] = fmaf(my, f.y, a[5]);
  f = __half22float2(__builtin_bit_cast(__half2, raw.w)); a[6] = fmaf(my, f.x, a[6]); a[7] = fmaf(my, f.y, a[7]);
}

__global__ __launch_bounds__(256) void gat_aggregate(
    const __half2* __restrict__ hb,
    const float* __restrict__ as_, const float* __restrict__ ad_,
    const int* __restrict__ row_ptr, const int* __restrict__ col,
    const int* __restrict__ perm,
    const float* __restrict__ bias, float* __restrict__ out, int n, int npad) {
  int wv = (int)((blockIdx.x * blockDim.x + threadIdx.x) >> 6);
  int lane = threadIdx.x & 63;
  int g = lane >> 4, q = lane & 15;
  int idx = wv * 4 + g;
  if (idx >= npad) return;
  int d = perm[idx];
  if (d >= n) return;  // sentinel slots
  int hidx = (q >= 8) ? 1 : 0;
  int beg = row_ptr[d], end = row_ptr[d + 1];
  const uint4* hb4 = (const uint4*)hb;   // 16 uint4 per node (256 B)

  float ad_my = ad_[d * 2 + hidx];

  float a[8] = {};
  // self-loop (not in CSR)
  float asv = as_[d * 2 + hidx];
  float my = __expf(leaky(asv + ad_my));
  uint4 raw = hb4[(size_t)d * 16 + q];
  fma8(a, my, raw);
  float dpart = my;

  int k = beg;
  for (; k + 3 < end; k += 4) {
    int s0 = col[k], s1 = col[k + 1], s2 = col[k + 2], s3 = col[k + 3];
    float e0 = as_[s0 * 2 + hidx];
    float e1 = as_[s1 * 2 + hidx];
    float e2 = as_[s2 * 2 + hidx];
    float e3 = as_[s3 * 2 + hidx];
    uint4 r0 = hb4[(size_t)s0 * 16 + q];
    uint4 r1 = hb4[(size_t)s1 * 16 + q];
    uint4 r2 = hb4[(size_t)s2 * 16 + q];
    uint4 r3 = hb4[(size_t)s3 * 16 + q];
    float m0 = __expf(leaky(e0 + ad_my));
    float m1 = __expf(leaky(e1 + ad_my));
    float m2 = __expf(leaky(e2 + ad_my));
    float m3 = __expf(leaky(e3 + ad_my));
    fma8(a, m0, r0); fma8(a, m1, r1); fma8(a, m2, r2); fma8(a, m3, r3);
    dpart += m0 + m1 + m2 + m3;
  }
  for (; k < end; k++) {  // tail 0..3
    int s = col[k];
    float e = as_[s * 2 + hidx];
    uint4 r = hb4[(size_t)s * 16 + q];
    float m = __expf(leaky(e + ad_my));
    fma8(a, m, r);
    dpart += m;
  }

  // head swap within the 16-lane group (serves all 4 nodes of the wave)
  float b[8];
#pragma unroll
  for (int i = 0; i < 8; i++) b[i] = __shfl_xor(a[i], 8);
  float denO = __shfl_xor(dpart, 8);

  if (q < 8) {  // channels 8q..8q+7
    float rr0 = 1.f / (dpart + 1e-16f), rr1 = 1.f / (denO + 1e-16f);
    float4 bl = *(const float4*)&bias[q * 8];
    float4 bh = *(const float4*)&bias[q * 8 + 4];
    f32x4 o0, o1;
    o0.x = 0.5f * (a[0] * rr0 + b[0] * rr1) + bl.x;
    o0.y = 0.5f * (a[1] * rr0 + b[1] * rr1) + bl.y;
    o0.z = 0.5f * (a[2] * rr0 + b[2] * rr1) + bl.z;
    o0.w = 0.5f * (a[3] * rr0 + b[3] * rr1) + bl.w;
    o1.x = 0.5f * (a[4] * rr0 + b[4] * rr1) + bh.x;
    o1.y = 0.5f * (a[5] * rr0 + b[5] * rr1) + bh.y;
    o1.z = 0.5f * (a[6] * rr0 + b[6] * rr1) + bh.z;
    o1.w = 0.5f * (a[7] * rr0 + b[7] * rr1) + bh.w;
    f32x4* outp = (f32x4*)&out[(size_t)d * 64 + q * 8];
    __builtin_nontemporal_store(o0, outp);
    __builtin_nontemporal_store(o1, outp + 1);
  }
}

// ---------------- MLP head: fused tiled GEMM (64 nodes / block) --------------
// a1 staging applies BN(layer3 scsh)+ReLU to the raw aggregate output.
__global__ __launch_bounds__(256) void mlp_head_tiled(
    const float* __restrict__ h3raw, const float* __restrict__ scsh,
    const float* __restrict__ x,
    const float* __restrict__ mW1, const float* __restrict__ mb1,
    const float* __restrict__ mW2, const float* __restrict__ mb2,
    const float* __restrict__ pW, const float* __restrict__ pb,
    const float* __restrict__ vW, const float* __restrict__ vb,
    float* __restrict__ out, int n) {
  __shared__ float lds[13632];
  float* a1  = lds;           // 64*68 = 4352
  float* ctx = lds + 4352;    // 64*8  = 512
  float* a2  = lds + 4864;    // 64*68 = 4352
  float* w1  = lds + 9216;    // 69*64 = 4416
  float* w2  = lds;           // aliases a1 (dead after GEMM1)

  int t = threadIdx.x;
  int node0 = blockIdx.x * 64;
  int rows = min(64, n - node0);

#pragma unroll
  for (int i = 0; i < 4; i++) {
    int flat = t + i * 256;
    int r = flat >> 4, kc = flat & 15;
    float4 v = make_float4(0.f, 0.f, 0.f, 0.f);
    if (r < rows) v = *(const float4*)&h3raw[(size_t)(node0 + r) * 64 + kc * 4];
    float4 sc4 = *(const float4*)&scsh[kc * 4];
    float4 sh4 = *(const float4*)&scsh[64 + kc * 4];
    v.x = fmaxf(fmaf(v.x, sc4.x, sh4.x), 0.f);
    v.y = fmaxf(fmaf(v.y, sc4.y, sh4.y), 0.f);
    v.z = fmaxf(fmaf(v.z, sc4.z, sh4.z), 0.f);
    v.w = fmaxf(fmaf(v.w, sc4.w, sh4.w), 0.f);
    *(float4*)&a1[r * 68 + kc * 4] = v;
  }
  for (int i = t; i < 320; i += 256) {
    int r = i / 5, j = i % 5;
    ctx[r * 8 + j] = (r < rows) ? x[(size_t)(node0 + r) * 16 + 9 + j] : 0.f;
  }
#pragma unroll
  for (int i = 0; i < 5; i++) {
    int flat = t + i * 256;
    if (flat < 1104) *(float4*)&w1[flat * 4] = *(const float4*)&mW1[flat * 4];
  }
  __syncthreads();

  int tc = t & 15, tr = t >> 4;
  int c0 = tc * 4, r0 = tr * 4;

  float acc[4][4] = {};
  for (int k = 0; k < 64; k += 4) {
    float4 av[4], wv[4];
#pragma unroll
    for (int i = 0; i < 4; i++) av[i] = *(const float4*)&a1[(r0 + i) * 68 + k];
#pragma unroll
    for (int j = 0; j < 4; j++) wv[j] = *(const float4*)&w1[(k + j) * 64 + c0];
#pragma unroll
    for (int i = 0; i < 4; i++) {
      const float* ai = (const float*)&av[i];
#pragma unroll
      for (int kk = 0; kk < 4; kk++) {
        const float* wr = (const float*)&wv[kk];
        acc[i][0] = fmaf(ai[kk], wr[0], acc[i][0]);
        acc[i][1] = fmaf(ai[kk], wr[1], acc[i][1]);
        acc[i][2] = fmaf(ai[kk], wr[2], acc[i][2]);
        acc[i][3] = fmaf(ai[kk], wr[3], acc[i][3]);
      }
    }
  }
#pragma unroll
  for (int k = 64; k < 69; k++) {
    float4 wv = *(const float4*)&w1[k * 64 + c0];
    const float* wr = (const float*)&wv;
#pragma unroll
    for (int i = 0; i < 4; i++) {
      float a = ctx[(r0 + i) * 8 + (k - 64)];
      acc[i][0] = fmaf(a, wr[0], acc[i][0]);
      acc[i][1] = fmaf(a, wr[1], acc[i][1]);
      acc[i][2] = fmaf(a, wr[2], acc[i][2]);
      acc[i][3] = fmaf(a, wr[3], acc[i][3]);
    }
  }
  float b1v0 = mb1[c0], b1v1 = mb1[c0 + 1], b1v2 = mb1[c0 + 2], b1v3 = mb1[c0 + 3];
#pragma unroll
  for (int i = 0; i < 4; i++) {
    float4 t1;
    t1.x = fmaxf(acc[i][0] + b1v0, 0.f);
    t1.y = fmaxf(acc[i][1] + b1v1, 0.f);
    t1.z = fmaxf(acc[i][2] + b1v2, 0.f);
    t1.w = fmaxf(acc[i][3] + b1v3, 0.f);
    *(float4*)&a2[(r0 + i) * 68 + c0] = t1;
  }
  __syncthreads();

#pragma unroll
  for (int i = 0; i < 4; i++) {
    int flat = t + i * 256;
    *(float4*)&w2[flat * 4] = *(const float4*)&mW2[flat * 4];
  }
  __syncthreads();

  float acc2[4][4] = {};
  for (int k = 0; k < 64; k += 4) {
    float4 av[4], wv[4];
#pragma unroll
    for (int i = 0; i < 4; i++) av[i] = *(const float4*)&a2[(r0 + i) * 68 + k];
#pragma unroll
    for (int j = 0; j < 4; j++) wv[j] = *(const float4*)&w2[(k + j) * 64 + c0];
#pragma unroll
    for (int i = 0; i < 4; i++) {
      const float* ai = (const float*)&av[i];
#pragma unroll
      for (int kk = 0; kk < 4; kk++) {
        const float* wr = (const float*)&wv[kk];
        acc2[i][0] = fmaf(ai[kk], wr[0], acc2[i][0]);
        acc2[i][1] = fmaf(ai[kk], wr[1], acc2[i][1]);
        acc2[i][2] = fmaf(ai[kk], wr[2], acc2[i][2]);
        acc2[i][3] = fmaf(ai[kk], wr[3], acc2[i][3]);
      }
    }
  }

  float b2v[4], pwv[4], vwv[4];
#pragma unroll
  for (int j = 0; j < 4; j++) {
    b2v[j] = mb2[c0 + j];
    pwv[j] = pW[c0 + j];
    vwv[j] = vW[c0 + j];
  }
  float p[4], v[4];
#pragma unroll
  for (int i = 0; i < 4; i++) {
    float ps = 0.f, vs = 0.f;
#pragma unroll
    for (int j = 0; j < 4; j++) {
      float u = acc2[i][j] + b2v[j];
      ps = fmaf(u, pwv[j], ps);
      vs = fmaf(u, vwv[j], vs);
    }
    p[i] = ps; v[i] = vs;
  }
#pragma unroll
  for (int off = 1; off < 16; off <<= 1) {
#pragma unroll
    for (int i = 0; i < 4; i++) {
      p[i] += __shfl_xor(p[i], off);
      v[i] += __shfl_xor(v[i], off);
    }
  }
  if (tc == 0) {
    float pbs = pb[0], vbs = vb[0];
#pragma unroll
    for (int i = 0; i < 4; i++) {
      int r = r0 + i;
      if (r < rows) {
        out[node0 + r] = p[i] + pbs;
        out[n + node0 + r] = v[i] + vbs;
      }
    }
  }
}

extern "C" void kernel_launch(void* const* d_in, const int* in_sizes, int n_in,
                              void* d_out, int out_size, void* d_ws, size_t ws_size,
                              hipStream_t stream) {
  const float* x = (const float*)d_in[0];
  const int* ei = (const int*)d_in[1];
  const float* W[3]  = {(const float*)d_in[2],  (const float*)d_in[8],  (const float*)d_in[14]};
  const float* AS[3] = {(const float*)d_in[3],  (const float*)d_in[9],  (const float*)d_in[15]};
  const float* AD[3] = {(const float*)d_in[4],  (const float*)d_in[10], (const float*)d_in[16]};
  const float* B[3]  = {(const float*)d_in[5],  (const float*)d_in[11], (const float*)d_in[17]};
  const float* G[3]  = {(const float*)d_in[6],  (const float*)d_in[12], (const float*)d_in[18]};
  const float* BE[3] = {(const float*)d_in[7],  (const float*)d_in[13], (const float*)d_in[19]};
  const float* mW1 = (const float*)d_in[20];
  const float* mb1 = (const float*)d_in[21];
  const float* mW2 = (const float*)d_in[22];
  const float* mb2 = (const float*)d_in[23];
  const float* pW  = (const float*)d_in[24];
  const float* pb  = (const float*)d_in[25];
  const float* vW  = (const float*)d_in[26];
  const float* vb  = (const float*)d_in[27];

  const int N = in_sizes[0] / 16;
  const int E = in_sizes[1] / 2;
  const int* srcp = ei;
  const int* dstp = ei + E;

  const int nbk = (N + 255) >> 8;
  const int npad = nbk << 8;  // perm index space (sentinel-padded)

  // workspace carve-up (~65 MB)
  float* bufB  = (float*)d_ws;               // N*64  raw aggregate output
  float* hbuf  = bufB + (size_t)N * 64;      // N*64 half2 region (N*64 f32 bytes)
  float* as_   = hbuf + (size_t)N * 64;      // N*2
  float* ad_   = as_ + (size_t)N * 2;        // N*2
  float* stats = ad_ + (size_t)N * 2;        // NSL*128
  float* scsh  = stats + NSL * 128;          // 128
  int* row_ptr = (int*)(scsh + 128);         // N+1
  int* bcnt    = row_ptr + (N + 1);          // 512
  int* ctr     = bcnt + 512;                 // 4 (bn_stats done-counter)
  int* boff    = ctr + 4;                    // 512
  int* bcur    = boff + 512;                 // 512
  int* perm    = bcur + 512;                 // npad (degree-rank order)
  int* col     = perm + npad;                // E ints (sorted CSR, src only)
  int2* ebuf   = (int2*)(col + E);           // E int2 (staging)
  __half2* hb  = (__half2*)hbuf;

  const float inv_n = 1.0f / (float)N;

  // ---- CSR build: binned counting sort (R17 formulation) + degree-rank perm
  hipMemsetAsync(bcnt, 0, sizeof(int) * 516, stream);  // bcnt + ctr
  bucket_hist<<<256, 256, 0, stream>>>(dstp, bcnt, E);
  bucket_scan<<<1, 512, 0, stream>>>(bcnt, boff, bcur, nbk);
  bin_scatter<<<(E + 8191) / 8192, 256, 0, stream>>>(srcp, dstp, bcur, ebuf, E);
  bucket_sort<<<nbk, 256, 0, stream>>>(ebuf, boff, col, row_ptr, perm, E, N, nbk);

  const int tiles = (N + 63) / 64;
  const int agg_blocks = npad / 16;  // 4 nodes/wave, 4 waves/block

  // ---- 3 GAT layers (BN+ReLU fused into the next consumer via scsh;
  //      bn_finalize fused into bn_stats via last-block pattern)
  for (int l = 0; l < 3; l++) {
    if (l == 0)
      gat_project_mfma<16, false><<<tiles, 256, 0, stream>>>(x, scsh, W[l], AS[l], AD[l],
                                                             hb, as_, ad_, N);
    else
      gat_project_mfma<64, true><<<tiles, 256, 0, stream>>>(bufB, scsh, W[l], AS[l], AD[l],
                                                            hb, as_, ad_, N);
    gat_aggregate<<<agg_blocks, 256, 0, stream>>>(hb, as_, ad_, row_ptr, col, perm,
                                                  B[l], bufB, N, npad);
    bn_stats<<<NSL, 256, 0, stream>>>(bufB, stats, G[l], BE[l], scsh, ctr, inv_n, N);
  }

  // ---- MLP head -> (logits, value); applies layer-3 BN+ReLU to bufB
  mlp_head_tiled<<<tiles, 256, 0, stream>>>(bufB, scsh, x, mW1, mb1, mW2, mb2,
                                            pW, pb, vW, vb, (float*)d_out, N);
}

// Round 10
// 504.281 us; speedup vs baseline: 1.2268x; 1.2268x over previous
//
#include <hip/hip_runtime.h>
#include <hip/hip_fp16.h>

// N=100000 nodes, E=1000000 edges, D_IN=16, H=2, C=64.
// 3x (GAT -> BN -> ReLU), then MLP head -> (logits, value) concat in d_out.
// R28 = R27 minus the bn_stats last-block fusion (R27 counters: device-scope
// __threadfence on 8-XCD gfx950 = L2 writeback/invalidate per block; 256
// blocks x 2 fences serialized -> bn_stats 5->65us. Grid-wide handoffs are
// priced per-FENCE on this chip; separate dispatches are the cheap fence).
// KEPT from R27: degree-rank perm (bucket_sort counting-sorts each 256-node
// chunk by degree; aggregate visits nodes in perm order so the 4 node-groups
// of a wave have near-equal degree -> no max-of-4-Poisson divergence tax;
// aggregate dropped out of top-5, est ~35us). Kept: R26 MFMA fp16 projection
// (matrix pipe), R24 aggregate shape, NT out stores, R17 CSR build,
// slice-write bn_stats + separate bn_finalize, scsh BN fusion into consumers.

__device__ __forceinline__ float leaky(float x) { return x > 0.f ? x : 0.2f * x; }

typedef float f32x4 __attribute__((ext_vector_type(4)));
typedef _Float16 f16x8 __attribute__((ext_vector_type(8)));

#define BCAP 4096  // max edges per 256-dst bucket (mean ~2560)
#define NSL 256    // bn_stats slices

// ---------------- CSR build ----------------
__global__ void bucket_hist(const int* __restrict__ dst, int* __restrict__ bcnt, int E) {
  __shared__ int cnt[512];
  int t = threadIdx.x;
  cnt[t] = 0; cnt[t + 256] = 0;
  __syncthreads();
  for (int e = blockIdx.x * blockDim.x + t; e < E; e += gridDim.x * blockDim.x)
    atomicAdd(&cnt[dst[e] >> 8], 1);
  __syncthreads();
  for (int i = t; i < 512; i += 256)
    if (cnt[i]) atomicAdd(&bcnt[i], cnt[i]);
}

__global__ void bucket_scan(const int* __restrict__ bcnt, int* __restrict__ boff,
                            int* __restrict__ bcur, int nbk) {
  __shared__ int temp[512];
  int t = threadIdx.x;  // 512 threads
  int v = (t < nbk) ? bcnt[t] : 0;
  temp[t] = v;
  __syncthreads();
  for (int off = 1; off < 512; off <<= 1) {
    int add = (t >= off) ? temp[t - off] : 0;
    __syncthreads();
    temp[t] += add;
    __syncthreads();
  }
  if (t < nbk) {
    int ex = temp[t] - v;
    boff[t] = ex;
    bcur[t] = ex;
  }
}

__global__ __launch_bounds__(256) void bin_scatter(
    const int* __restrict__ src, const int* __restrict__ dst,
    int* __restrict__ bcur, int2* __restrict__ ebuf, int E) {
  __shared__ int cnt[512];
  __shared__ int base[512];
  int t = threadIdx.x;
  int beg = blockIdx.x * 8192;
  int end = min(E, beg + 8192);
  cnt[t] = 0; cnt[t + 256] = 0;
  __syncthreads();
  for (int e = beg + t; e < end; e += 256)
    atomicAdd(&cnt[dst[e] >> 8], 1);
  __syncthreads();
  for (int i = t; i < 512; i += 256) {
    base[i] = cnt[i] ? atomicAdd(&bcur[i], cnt[i]) : 0;
    cnt[i] = 0;  // reuse as within-run cursor
  }
  __syncthreads();
  for (int e = beg + t; e < end; e += 256) {
    int d = dst[e];
    int bk = d >> 8;
    int off = atomicAdd(&cnt[bk], 1);
    ebuf[base[bk] + off] = make_int2(src[e], d);
  }
}

__global__ __launch_bounds__(256) void bucket_sort(
    const int2* __restrict__ ebuf, const int* __restrict__ boff,
    int* __restrict__ col, int* __restrict__ row_ptr, int* __restrict__ perm,
    int E, int n, int nbk) {
  __shared__ int2 eds[BCAP];
  __shared__ int dcnt[256];
  __shared__ int dbase[256];
  __shared__ int dexcl[256];
  __shared__ int dgh[32];
  int b = blockIdx.x, t = threadIdx.x;
  int S = boff[b];
  int Eend = (b + 1 < nbk) ? boff[b + 1] : E;
  int cnt = min(Eend - S, BCAP);
  for (int i = t; i < cnt; i += 256) eds[i] = ebuf[S + i];
  dcnt[t] = 0;
  if (t < 32) dgh[t] = 0;
  perm[(b << 8) + t] = n;  // sentinel fill (overwritten for valid ranks)
  __syncthreads();
  for (int i = t; i < cnt; i += 256) atomicAdd(&dcnt[eds[i].y & 255], 1);
  __syncthreads();
  int v = dcnt[t];
  dbase[t] = v;
  __syncthreads();
  for (int off = 1; off < 256; off <<= 1) {
    int add = (t >= off) ? dbase[t - off] : 0;
    __syncthreads();
    dbase[t] += add;
    __syncthreads();
  }
  int excl = dbase[t] - v;
  int d = (b << 8) + t;
  bool valid = (d < n);
  if (valid) row_ptr[d] = S + excl;
  if (b == nbk - 1 && t == 0) row_ptr[n] = E;
  // ---- degree-rank perm: counting sort of this chunk's nodes by degree
  int bin = min(v, 31);
  int within = 0;
  if (valid) within = atomicAdd(&dgh[bin], 1);
  __syncthreads();
  if (t == 0) {
    int s = 0;
    for (int i = 0; i < 32; i++) { int c = dgh[i]; dgh[i] = s; s += c; }
  }
  __syncthreads();
  if (valid) perm[(b << 8) + dgh[bin] + within] = d;
  // ---- edge scatter into sorted CSR
  dcnt[t] = 0;  // reuse as per-dst cursor
  dexcl[t] = excl;
  __syncthreads();
  for (int i = t; i < cnt; i += 256) {
    int2 e = eds[i];
    int dl = e.y & 255;
    int off = atomicAdd(&dcnt[dl], 1);
    col[S + dexcl[dl] + off] = e.x;
  }
}

// ---------------- BN stats (vectorized, slice writes) + finalize ----------
__global__ __launch_bounds__(256) void bn_stats(const float* __restrict__ h,
                                                float* __restrict__ stats, int n) {
  __shared__ float ssum[64], ssq[64];
  int t = threadIdx.x;
  if (t < 64) { ssum[t] = 0.f; ssq[t] = 0.f; }
  __syncthreads();
  const float4* h4 = (const float4*)h;
  size_t total4 = (size_t)n * 16;
  size_t stride = (size_t)gridDim.x * blockDim.x;   // multiple of 16
  int cbase = ((int)(((size_t)blockIdx.x * blockDim.x + t) & 15)) * 4;
  float s0 = 0.f, s1 = 0.f, s2 = 0.f, s3 = 0.f;
  float q0 = 0.f, q1 = 0.f, q2 = 0.f, q3 = 0.f;
  for (size_t i = (size_t)blockIdx.x * blockDim.x + t; i < total4; i += stride) {
    float4 v = h4[i];
    s0 += v.x; q0 = fmaf(v.x, v.x, q0);
    s1 += v.y; q1 = fmaf(v.y, v.y, q1);
    s2 += v.z; q2 = fmaf(v.z, v.z, q2);
    s3 += v.w; q3 = fmaf(v.w, v.w, q3);
  }
  atomicAdd(&ssum[cbase + 0], s0); atomicAdd(&ssq[cbase + 0], q0);
  atomicAdd(&ssum[cbase + 1], s1); atomicAdd(&ssq[cbase + 1], q1);
  atomicAdd(&ssum[cbase + 2], s2); atomicAdd(&ssq[cbase + 2], q2);
  atomicAdd(&ssum[cbase + 3], s3); atomicAdd(&ssq[cbase + 3], q3);
  __syncthreads();
  if (t < 64) {
    stats[blockIdx.x * 128 + t] = ssum[t];
    stats[blockIdx.x * 128 + 64 + t] = ssq[t];
  }
}

// reduce NSL slices -> scsh (scale/shift). 128 threads: t<64 sums, else sumsq.
__global__ void bn_finalize(const float* __restrict__ stats, const float* __restrict__ g,
                            const float* __restrict__ be, float* __restrict__ scsh,
                            float inv_n) {
  __shared__ float red[128];
  int t = threadIdx.x;  // 128
  int c = t & 63;
  int off = (t >> 6) * 64;  // 0 = sum, 64 = sumsq
  float acc = 0.f;
  for (int b = 0; b < NSL; b++) acc += stats[b * 128 + off + c];
  red[t] = acc;
  __syncthreads();
  if (t < 64) {
    float mean = red[t] * inv_n;
    float var = red[64 + t] * inv_n - mean * mean;
    float sc = rsqrtf(var + 1e-5f) * g[t];
    scsh[t] = sc;
    scsh[64 + t] = be[t] - mean * sc;
  }
}

// ---------------- GAT projection: MFMA fp16, 64 nodes x 128 cols ------------
// h = act @ W on the matrix pipe. 4 waves; wave w owns node rows w*16..+15,
// all 8 col-tiles. A[64][KP] and W^T[128][KP] staged fp16 in LDS, KP = KE+8
// (odd 16B stride -> conflict-free ds_read_b128 fragments). K=16 zero-padded
// to KE=32. C/D layout (m89): col=lane&15, row=(lane>>4)*4+reg.
template <int K, bool BN>
__global__ __launch_bounds__(256) void gat_project_mfma(
    const float* __restrict__ act, const float* __restrict__ scsh,
    const float* __restrict__ W,
    const float* __restrict__ att_s, const float* __restrict__ att_d,
    __half2* __restrict__ hb, float* __restrict__ as_,
    float* __restrict__ ad_, int n) {
  constexpr int KE = (K < 32) ? 32 : K;   // effective (padded) K
  constexpr int KP = KE + 8;              // LDS stride in halves
  constexpr int STAGE = 64 * KP * 2 + 128 * KP * 2;
  constexpr int HSZ = 64 * 136 * 2;
  constexpr int LDSZ = (STAGE > HSZ) ? STAGE : HSZ;
  __shared__ __align__(16) char ldsb[LDSZ];
  __shared__ float attS[256];
  __half* aH = (__half*)ldsb;                      // [64][KP]
  __half* wT = (__half*)(ldsb + 64 * KP * 2);      // [128][KP] (transposed W)
  __half* hS = (__half*)ldsb;                      // [64][136], aliases after barrier

  int t = threadIdx.x;
  int node0 = blockIdx.x * 64;
  int rows = min(64, n - node0);

  // ---- stage A: fp32 -> fp16, BN+ReLU fused; zero-pad r>=rows and k>=K
  constexpr int ACH = 64 * KE / 4;
  for (int i = t; i < ACH; i += 256) {
    int r = i / (KE / 4), kc = i % (KE / 4);
    float4 v = make_float4(0.f, 0.f, 0.f, 0.f);
    if (r < rows && kc * 4 < K)
      v = *(const float4*)&act[(size_t)(node0 + r) * K + kc * 4];
    if (BN) {
      float4 sc4 = *(const float4*)&scsh[kc * 4];
      float4 sh4 = *(const float4*)&scsh[64 + kc * 4];
      v.x = fmaxf(fmaf(v.x, sc4.x, sh4.x), 0.f);
      v.y = fmaxf(fmaf(v.y, sc4.y, sh4.y), 0.f);
      v.z = fmaxf(fmaf(v.z, sc4.z, sh4.z), 0.f);
      v.w = fmaxf(fmaf(v.w, sc4.w, sh4.w), 0.f);
    }
    __half2 h01 = __floats2half2_rn(v.x, v.y);
    __half2 h23 = __floats2half2_rn(v.z, v.w);
    uint2 pk = make_uint2(__builtin_bit_cast(unsigned, h01),
                          __builtin_bit_cast(unsigned, h23));
    *(uint2*)&aH[r * KP + kc * 4] = pk;
  }
  // ---- stage W^T: wT[c][k] fp16 (coalesced global read)
  for (int i = t; i < KE * 128; i += 256) {
    int k = i >> 7, c = i & 127;
    float wv = (k < K) ? W[k * 128 + c] : 0.f;
    wT[c * KP + k] = __float2half(wv);
  }
  attS[t] = (t < 128) ? att_s[t] : att_d[t - 128];
  __syncthreads();

  int w = t >> 6, l = t & 63;
  int cl = l & 15, r4 = l >> 4;
  int w16 = w * 16;

  f32x4 acc[8] = {};
#pragma unroll
  for (int ks = 0; ks < KE / 32; ks++) {
    f16x8 av = *(const f16x8*)&aH[(w16 + cl) * KP + ks * 32 + r4 * 8];
#pragma unroll
    for (int ct = 0; ct < 8; ct++) {
      f16x8 bv = *(const f16x8*)&wT[(ct * 16 + cl) * KP + ks * 32 + r4 * 8];
      acc[ct] = __builtin_amdgcn_mfma_f32_16x16x32_f16(av, bv, acc[ct], 0, 0, 0);
    }
  }

  // ---- att scores from accumulators (per-row dot with att vectors)
  float ats[8], atd[8];
#pragma unroll
  for (int ct = 0; ct < 8; ct++) {
    ats[ct] = attS[ct * 16 + cl];
    atd[ct] = attS[128 + ct * 16 + cl];
  }
#pragma unroll
  for (int i = 0; i < 4; i++) {
    float s0 = 0.f, s1 = 0.f, d0 = 0.f, d1 = 0.f;
#pragma unroll
    for (int ct = 0; ct < 4; ct++) {
      s0 = fmaf(acc[ct][i], ats[ct], s0);
      d0 = fmaf(acc[ct][i], atd[ct], d0);
      s1 = fmaf(acc[ct + 4][i], ats[ct + 4], s1);
      d1 = fmaf(acc[ct + 4][i], atd[ct + 4], d1);
    }
#pragma unroll
    for (int off = 1; off < 16; off <<= 1) {
      s0 += __shfl_xor(s0, off); s1 += __shfl_xor(s1, off);
      d0 += __shfl_xor(d0, off); d1 += __shfl_xor(d1, off);
    }
    int rloc = w16 + r4 * 4 + i;
    if (rloc < rows) {
      int row = node0 + rloc;
      if (cl == 0) as_[row * 2] = s0;
      else if (cl == 1) as_[row * 2 + 1] = s1;
      else if (cl == 2) ad_[row * 2] = d0;
      else if (cl == 3) ad_[row * 2 + 1] = d1;
    }
  }

  __syncthreads();  // aH/wT dead -> reuse as hS
  // ---- C fragments -> hS fp16 [64][136]
#pragma unroll
  for (int ct = 0; ct < 8; ct++)
#pragma unroll
    for (int i = 0; i < 4; i++)
      hS[(w16 + r4 * 4 + i) * 136 + ct * 16 + cl] = __float2half(acc[ct][i]);
  __syncthreads();
  // ---- hS -> hb, coalesced 16B chunks (256B per node row)
#pragma unroll
  for (int it = 0; it < 4; it++) {
    int flat = t + it * 256;
    int nd = flat >> 4, ch = flat & 15;
    if (nd < rows)
      *(uint4*)((char*)hb + (((size_t)(node0 + nd)) << 8) + (ch << 4)) =
          *(const uint4*)((const char*)hS + nd * 272 + (ch << 4));
  }
}

// ---------------- GAT aggregation: 16 lanes/node, 4 nodes/wave (R24) --------
// Nodes visited in degree-rank perm order -> the 4 groups of a wave have
// near-equal degree (no max-of-4 divergence tax). Lane q accumulates its 8
// channels of head (q>=8) over ALL edges; 4-deep unroll; redundant per-lane
// den; 9-op head-swap epilogue; NT out stores.
__device__ __forceinline__ void fma8(float* a, float my, uint4 raw) {
  float2 f;
  f = __half22float2(__builtin_bit_cast(__half2, raw.x)); a[0] = fmaf(my, f.x, a[0]); a[1] = fmaf(my, f.y, a[1]);
  f = __half22float2(__builtin_bit_cast(__half2, raw.y)); a[2] = fmaf(my, f.x, a[2]); a[3] = fmaf(my, f.y, a[3]);
  f = __half22float2(__builtin_bit_cast(__half2, raw.z)); a[4] = fmaf(my, f.x, a[4]); a[5] = fmaf(my, f.y, a[5]);
  f = __half22float2(__builtin_bit_cast(__half2, raw.w)); a[6] = fmaf(my, f.x, a[6]); a[7] = fmaf(my, f.y, a[7]);
}

__global__ __launch_bounds__(256) void gat_aggregate(
    const __half2* __restrict__ hb,
    const float* __restrict__ as_, const float* __restrict__ ad_,
    const int* __restrict__ row_ptr, const int* __restrict__ col,
    const int* __restrict__ perm,
    const float* __restrict__ bias, float* __restrict__ out, int n, int npad) {
  int wv = (int)((blockIdx.x * blockDim.x + threadIdx.x) >> 6);
  int lane = threadIdx.x & 63;
  int g = lane >> 4, q = lane & 15;
  int idx = wv * 4 + g;
  if (idx >= npad) return;
  int d = perm[idx];
  if (d >= n) return;  // sentinel slots
  int hidx = (q >= 8) ? 1 : 0;
  int beg = row_ptr[d], end = row_ptr[d + 1];
  const uint4* hb4 = (const uint4*)hb;   // 16 uint4 per node (256 B)

  float ad_my = ad_[d * 2 + hidx];

  float a[8] = {};
  // self-loop (not in CSR)
  float asv = as_[d * 2 + hidx];
  float my = __expf(leaky(asv + ad_my));
  uint4 raw = hb4[(size_t)d * 16 + q];
  fma8(a, my, raw);
  float dpart = my;

  int k = beg;
  for (; k + 3 < end; k += 4) {
    int s0 = col[k], s1 = col[k + 1], s2 = col[k + 2], s3 = col[k + 3];
    float e0 = as_[s0 * 2 + hidx];
    float e1 = as_[s1 * 2 + hidx];
    float e2 = as_[s2 * 2 + hidx];
    float e3 = as_[s3 * 2 + hidx];
    uint4 r0 = hb4[(size_t)s0 * 16 + q];
    uint4 r1 = hb4[(size_t)s1 * 16 + q];
    uint4 r2 = hb4[(size_t)s2 * 16 + q];
    uint4 r3 = hb4[(size_t)s3 * 16 + q];
    float m0 = __expf(leaky(e0 + ad_my));
    float m1 = __expf(leaky(e1 + ad_my));
    float m2 = __expf(leaky(e2 + ad_my));
    float m3 = __expf(leaky(e3 + ad_my));
    fma8(a, m0, r0); fma8(a, m1, r1); fma8(a, m2, r2); fma8(a, m3, r3);
    dpart += m0 + m1 + m2 + m3;
  }
  for (; k < end; k++) {  // tail 0..3
    int s = col[k];
    float e = as_[s * 2 + hidx];
    uint4 r = hb4[(size_t)s * 16 + q];
    float m = __expf(leaky(e + ad_my));
    fma8(a, m, r);
    dpart += m;
  }

  // head swap within the 16-lane group (serves all 4 nodes of the wave)
  float b[8];
#pragma unroll
  for (int i = 0; i < 8; i++) b[i] = __shfl_xor(a[i], 8);
  float denO = __shfl_xor(dpart, 8);

  if (q < 8) {  // channels 8q..8q+7
    float rr0 = 1.f / (dpart + 1e-16f), rr1 = 1.f / (denO + 1e-16f);
    float4 bl = *(const float4*)&bias[q * 8];
    float4 bh = *(const float4*)&bias[q * 8 + 4];
    f32x4 o0, o1;
    o0.x = 0.5f * (a[0] * rr0 + b[0] * rr1) + bl.x;
    o0.y = 0.5f * (a[1] * rr0 + b[1] * rr1) + bl.y;
    o0.z = 0.5f * (a[2] * rr0 + b[2] * rr1) + bl.z;
    o0.w = 0.5f * (a[3] * rr0 + b[3] * rr1) + bl.w;
    o1.x = 0.5f * (a[4] * rr0 + b[4] * rr1) + bh.x;
    o1.y = 0.5f * (a[5] * rr0 + b[5] * rr1) + bh.y;
    o1.z = 0.5f * (a[6] * rr0 + b[6] * rr1) + bh.z;
    o1.w = 0.5f * (a[7] * rr0 + b[7] * rr1) + bh.w;
    f32x4* outp = (f32x4*)&out[(size_t)d * 64 + q * 8];
    __builtin_nontemporal_store(o0, outp);
    __builtin_nontemporal_store(o1, outp + 1);
  }
}

// ---------------- MLP head: fused tiled GEMM (64 nodes / block) --------------
// a1 staging applies BN(layer3 scsh)+ReLU to the raw aggregate output.
__global__ __launch_bounds__(256) void mlp_head_tiled(
    const float* __restrict__ h3raw, const float* __restrict__ scsh,
    const float* __restrict__ x,
    const float* __restrict__ mW1, const float* __restrict__ mb1,
    const float* __restrict__ mW2, const float* __restrict__ mb2,
    const float* __restrict__ pW, const float* __restrict__ pb,
    const float* __restrict__ vW, const float* __restrict__ vb,
    float* __restrict__ out, int n) {
  __shared__ float lds[13632];
  float* a1  = lds;           // 64*68 = 4352
  float* ctx = lds + 4352;    // 64*8  = 512
  float* a2  = lds + 4864;    // 64*68 = 4352
  float* w1  = lds + 9216;    // 69*64 = 4416
  float* w2  = lds;           // aliases a1 (dead after GEMM1)

  int t = threadIdx.x;
  int node0 = blockIdx.x * 64;
  int rows = min(64, n - node0);

#pragma unroll
  for (int i = 0; i < 4; i++) {
    int flat = t + i * 256;
    int r = flat >> 4, kc = flat & 15;
    float4 v = make_float4(0.f, 0.f, 0.f, 0.f);
    if (r < rows) v = *(const float4*)&h3raw[(size_t)(node0 + r) * 64 + kc * 4];
    float4 sc4 = *(const float4*)&scsh[kc * 4];
    float4 sh4 = *(const float4*)&scsh[64 + kc * 4];
    v.x = fmaxf(fmaf(v.x, sc4.x, sh4.x), 0.f);
    v.y = fmaxf(fmaf(v.y, sc4.y, sh4.y), 0.f);
    v.z = fmaxf(fmaf(v.z, sc4.z, sh4.z), 0.f);
    v.w = fmaxf(fmaf(v.w, sc4.w, sh4.w), 0.f);
    *(float4*)&a1[r * 68 + kc * 4] = v;
  }
  for (int i = t; i < 320; i += 256) {
    int r = i / 5, j = i % 5;
    ctx[r * 8 + j] = (r < rows) ? x[(size_t)(node0 + r) * 16 + 9 + j] : 0.f;
  }
#pragma unroll
  for (int i = 0; i < 5; i++) {
    int flat = t + i * 256;
    if (flat < 1104) *(float4*)&w1[flat * 4] = *(const float4*)&mW1[flat * 4];
  }
  __syncthreads();

  int tc = t & 15, tr = t >> 4;
  int c0 = tc * 4, r0 = tr * 4;

  float acc[4][4] = {};
  for (int k = 0; k < 64; k += 4) {
    float4 av[4], wv[4];
#pragma unroll
    for (int i = 0; i < 4; i++) av[i] = *(const float4*)&a1[(r0 + i) * 68 + k];
#pragma unroll
    for (int j = 0; j < 4; j++) wv[j] = *(const float4*)&w1[(k + j) * 64 + c0];
#pragma unroll
    for (int i = 0; i < 4; i++) {
      const float* ai = (const float*)&av[i];
#pragma unroll
      for (int kk = 0; kk < 4; kk++) {
        const float* wr = (const float*)&wv[kk];
        acc[i][0] = fmaf(ai[kk], wr[0], acc[i][0]);
        acc[i][1] = fmaf(ai[kk], wr[1], acc[i][1]);
        acc[i][2] = fmaf(ai[kk], wr[2], acc[i][2]);
        acc[i][3] = fmaf(ai[kk], wr[3], acc[i][3]);
      }
    }
  }
#pragma unroll
  for (int k = 64; k < 69; k++) {
    float4 wv = *(const float4*)&w1[k * 64 + c0];
    const float* wr = (const float*)&wv;
#pragma unroll
    for (int i = 0; i < 4; i++) {
      float a = ctx[(r0 + i) * 8 + (k - 64)];
      acc[i][0] = fmaf(a, wr[0], acc[i][0]);
      acc[i][1] = fmaf(a, wr[1], acc[i][1]);
      acc[i][2] = fmaf(a, wr[2], acc[i][2]);
      acc[i][3] = fmaf(a, wr[3], acc[i][3]);
    }
  }
  float b1v0 = mb1[c0], b1v1 = mb1[c0 + 1], b1v2 = mb1[c0 + 2], b1v3 = mb1[c0 + 3];
#pragma unroll
  for (int i = 0; i < 4; i++) {
    float4 t1;
    t1.x = fmaxf(acc[i][0] + b1v0, 0.f);
    t1.y = fmaxf(acc[i][1] + b1v1, 0.f);
    t1.z = fmaxf(acc[i][2] + b1v2, 0.f);
    t1.w = fmaxf(acc[i][3] + b1v3, 0.f);
    *(float4*)&a2[(r0 + i) * 68 + c0] = t1;
  }
  __syncthreads();

#pragma unroll
  for (int i = 0; i < 4; i++) {
    int flat = t + i * 256;
    *(float4*)&w2[flat * 4] = *(const float4*)&mW2[flat * 4];
  }
  __syncthreads();

  float acc2[4][4] = {};
  for (int k = 0; k < 64; k += 4) {
    float4 av[4], wv[4];
#pragma unroll
    for (int i = 0; i < 4; i++) av[i] = *(const float4*)&a2[(r0 + i) * 68 + k];
#pragma unroll
    for (int j = 0; j < 4; j++) wv[j] = *(const float4*)&w2[(k + j) * 64 + c0];
#pragma unroll
    for (int i = 0; i < 4; i++) {
      const float* ai = (const float*)&av[i];
#pragma unroll
      for (int kk = 0; kk < 4; kk++) {
        const float* wr = (const float*)&wv[kk];
        acc2[i][0] = fmaf(ai[kk], wr[0], acc2[i][0]);
        acc2[i][1] = fmaf(ai[kk], wr[1], acc2[i][1]);
        acc2[i][2] = fmaf(ai[kk], wr[2], acc2[i][2]);
        acc2[i][3] = fmaf(ai[kk], wr[3], acc2[i][3]);
      }
    }
  }

  float b2v[4], pwv[4], vwv[4];
#pragma unroll
  for (int j = 0; j < 4; j++) {
    b2v[j] = mb2[c0 + j];
    pwv[j] = pW[c0 + j];
    vwv[j] = vW[c0 + j];
  }
  float p[4], v[4];
#pragma unroll
  for (int i = 0; i < 4; i++) {
    float ps = 0.f, vs = 0.f;
#pragma unroll
    for (int j = 0; j < 4; j++) {
      float u = acc2[i][j] + b2v[j];
      ps = fmaf(u, pwv[j], ps);
      vs = fmaf(u, vwv[j], vs);
    }
    p[i] = ps; v[i] = vs;
  }
#pragma unroll
  for (int off = 1; off < 16; off <<= 1) {
#pragma unroll
    for (int i = 0; i < 4; i++) {
      p[i] += __shfl_xor(p[i], off);
      v[i] += __shfl_xor(v[i], off);
    }
  }
  if (tc == 0) {
    float pbs = pb[0], vbs = vb[0];
#pragma unroll
    for (int i = 0; i < 4; i++) {
      int r = r0 + i;
      if (r < rows) {
        out[node0 + r] = p[i] + pbs;
        out[n + node0 + r] = v[i] + vbs;
      }
    }
  }
}

extern "C" void kernel_launch(void* const* d_in, const int* in_sizes, int n_in,
                              void* d_out, int out_size, void* d_ws, size_t ws_size,
                              hipStream_t stream) {
  const float* x = (const float*)d_in[0];
  const int* ei = (const int*)d_in[1];
  const float* W[3]  = {(const float*)d_in[2],  (const float*)d_in[8],  (const float*)d_in[14]};
  const float* AS[3] = {(const float*)d_in[3],  (const float*)d_in[9],  (const float*)d_in[15]};
  const float* AD[3] = {(const float*)d_in[4],  (const float*)d_in[10], (const float*)d_in[16]};
  const float* B[3]  = {(const float*)d_in[5],  (const float*)d_in[11], (const float*)d_in[17]};
  const float* G[3]  = {(const float*)d_in[6],  (const float*)d_in[12], (const float*)d_in[18]};
  const float* BE[3] = {(const float*)d_in[7],  (const float*)d_in[13], (const float*)d_in[19]};
  const float* mW1 = (const float*)d_in[20];
  const float* mb1 = (const float*)d_in[21];
  const float* mW2 = (const float*)d_in[22];
  const float* mb2 = (const float*)d_in[23];
  const float* pW  = (const float*)d_in[24];
  const float* pb  = (const float*)d_in[25];
  const float* vW  = (const float*)d_in[26];
  const float* vb  = (const float*)d_in[27];

  const int N = in_sizes[0] / 16;
  const int E = in_sizes[1] / 2;
  const int* srcp = ei;
  const int* dstp = ei + E;

  const int nbk = (N + 255) >> 8;
  const int npad = nbk << 8;  // perm index space (sentinel-padded)

  // workspace carve-up (~65 MB)
  float* bufB  = (float*)d_ws;               // N*64  raw aggregate output
  float* hbuf  = bufB + (size_t)N * 64;      // N*64 half2 region (N*64 f32 bytes)
  float* as_   = hbuf + (size_t)N * 64;      // N*2
  float* ad_   = as_ + (size_t)N * 2;        // N*2
  float* stats = ad_ + (size_t)N * 2;        // NSL*128
  float* scsh  = stats + NSL * 128;          // 128
  int* row_ptr = (int*)(scsh + 128);         // N+1
  int* bcnt    = row_ptr + (N + 1);          // 512
  int* boff    = bcnt + 512;                 // 512
  int* bcur    = boff + 512;                 // 512
  int* perm    = bcur + 512;                 // npad (degree-rank order)
  int* col     = perm + npad;                // E ints (sorted CSR, src only)
  int2* ebuf   = (int2*)(col + E);           // E int2 (staging)
  __half2* hb  = (__half2*)hbuf;

  const float inv_n = 1.0f / (float)N;

  // ---- CSR build: binned counting sort (R17 formulation) + degree-rank perm
  hipMemsetAsync(bcnt, 0, sizeof(int) * 512, stream);
  bucket_hist<<<256, 256, 0, stream>>>(dstp, bcnt, E);
  bucket_scan<<<1, 512, 0, stream>>>(bcnt, boff, bcur, nbk);
  bin_scatter<<<(E + 8191) / 8192, 256, 0, stream>>>(srcp, dstp, bcur, ebuf, E);
  bucket_sort<<<nbk, 256, 0, stream>>>(ebuf, boff, col, row_ptr, perm, E, N, nbk);

  const int tiles = (N + 63) / 64;
  const int agg_blocks = npad / 16;  // 4 nodes/wave, 4 waves/block

  // ---- 3 GAT layers (BN+ReLU fused into the next consumer via scsh)
  for (int l = 0; l < 3; l++) {
    if (l == 0)
      gat_project_mfma<16, false><<<tiles, 256, 0, stream>>>(x, scsh, W[l], AS[l], AD[l],
                                                             hb, as_, ad_, N);
    else
      gat_project_mfma<64, true><<<tiles, 256, 0, stream>>>(bufB, scsh, W[l], AS[l], AD[l],
                                                            hb, as_, ad_, N);
    gat_aggregate<<<agg_blocks, 256, 0, stream>>>(hb, as_, ad_, row_ptr, col, perm,
                                                  B[l], bufB, N, npad);
    bn_stats<<<NSL, 256, 0, stream>>>(bufB, stats, N);
    bn_finalize<<<1, 128, 0, stream>>>(stats, G[l], BE[l], scsh, inv_n);
  }

  // ---- MLP head -> (logits, value); applies layer-3 BN+ReLU to bufB
  mlp_head_tiled<<<tiles, 256, 0, stream>>>(bufB, scsh, x, mW1, mb1, mW2, mb2,
                                            pW, pb, vW, vb, (float*)d_out, N);
}

// Round 11
// 463.548 us; speedup vs baseline: 1.3346x; 1.0879x over previous
//
#include <hip/hip_runtime.h>
#include <hip/hip_fp16.h>

// N=100000 nodes, E=1000000 edges, D_IN=16, H=2, C=64.
// 3x (GAT -> BN -> ReLU), then MLP head -> (logits, value) concat in d_out.
// R29 = R26 (best verified, 471.5us) + mlp_head LDS shrink. R28 post-mortem:
// degree-rank perm REGRESSED aggregate 45.8->57.5us (FETCH +10MB, occ 66->46%)
// — scattering node visit order destroyed row_ptr/as_/hb L2 locality; the
// divergence tax it removed (~5us) was smaller than the locality it cost.
// Perm dropped; natural node order restored. NEW: mlp_head was 54.5KB LDS ->
// 2 blocks/CU; GEMM1 output now written IN-PLACE over a1 (regs hold it across
// a barrier) and w2 staged over w1 -> 37.1KB -> 4 blocks/CU, numerics
// identical. Kept: R26 MFMA fp16 projection (matrix pipe), R24 aggregate
// (16 lanes/node, 4 nodes/wave, 4-deep), NT out stores, R17 CSR build,
// slice-write bn_stats + separate bn_finalize (fence/atomic fusions both
// proven losers on 8-XCD gfx950), scsh BN fusion into consumers.

__device__ __forceinline__ float leaky(float x) { return x > 0.f ? x : 0.2f * x; }

typedef float f32x4 __attribute__((ext_vector_type(4)));
typedef _Float16 f16x8 __attribute__((ext_vector_type(8)));

#define BCAP 4096  // max edges per 256-dst bucket (mean ~2560)
#define NSL 256    // bn_stats slices

// ---------------- CSR build ----------------
__global__ void bucket_hist(const int* __restrict__ dst, int* __restrict__ bcnt, int E) {
  __shared__ int cnt[512];
  int t = threadIdx.x;
  cnt[t] = 0; cnt[t + 256] = 0;
  __syncthreads();
  for (int e = blockIdx.x * blockDim.x + t; e < E; e += gridDim.x * blockDim.x)
    atomicAdd(&cnt[dst[e] >> 8], 1);
  __syncthreads();
  for (int i = t; i < 512; i += 256)
    if (cnt[i]) atomicAdd(&bcnt[i], cnt[i]);
}

__global__ void bucket_scan(const int* __restrict__ bcnt, int* __restrict__ boff,
                            int* __restrict__ bcur, int nbk) {
  __shared__ int temp[512];
  int t = threadIdx.x;  // 512 threads
  int v = (t < nbk) ? bcnt[t] : 0;
  temp[t] = v;
  __syncthreads();
  for (int off = 1; off < 512; off <<= 1) {
    int add = (t >= off) ? temp[t - off] : 0;
    __syncthreads();
    temp[t] += add;
    __syncthreads();
  }
  if (t < nbk) {
    int ex = temp[t] - v;
    boff[t] = ex;
    bcur[t] = ex;
  }
}

__global__ __launch_bounds__(256) void bin_scatter(
    const int* __restrict__ src, const int* __restrict__ dst,
    int* __restrict__ bcur, int2* __restrict__ ebuf, int E) {
  __shared__ int cnt[512];
  __shared__ int base[512];
  int t = threadIdx.x;
  int beg = blockIdx.x * 8192;
  int end = min(E, beg + 8192);
  cnt[t] = 0; cnt[t + 256] = 0;
  __syncthreads();
  for (int e = beg + t; e < end; e += 256)
    atomicAdd(&cnt[dst[e] >> 8], 1);
  __syncthreads();
  for (int i = t; i < 512; i += 256) {
    base[i] = cnt[i] ? atomicAdd(&bcur[i], cnt[i]) : 0;
    cnt[i] = 0;  // reuse as within-run cursor
  }
  __syncthreads();
  for (int e = beg + t; e < end; e += 256) {
    int d = dst[e];
    int bk = d >> 8;
    int off = atomicAdd(&cnt[bk], 1);
    ebuf[base[bk] + off] = make_int2(src[e], d);
  }
}

__global__ __launch_bounds__(256) void bucket_sort(
    const int2* __restrict__ ebuf, const int* __restrict__ boff,
    int* __restrict__ col, int* __restrict__ row_ptr, int E, int n, int nbk) {
  __shared__ int2 eds[BCAP];
  __shared__ int dcnt[256];
  __shared__ int dbase[256];
  __shared__ int dexcl[256];
  int b = blockIdx.x, t = threadIdx.x;
  int S = boff[b];
  int Eend = (b + 1 < nbk) ? boff[b + 1] : E;
  int cnt = min(Eend - S, BCAP);
  for (int i = t; i < cnt; i += 256) eds[i] = ebuf[S + i];
  dcnt[t] = 0;
  __syncthreads();
  for (int i = t; i < cnt; i += 256) atomicAdd(&dcnt[eds[i].y & 255], 1);
  __syncthreads();
  int v = dcnt[t];
  dbase[t] = v;
  __syncthreads();
  for (int off = 1; off < 256; off <<= 1) {
    int add = (t >= off) ? dbase[t - off] : 0;
    __syncthreads();
    dbase[t] += add;
    __syncthreads();
  }
  int excl = dbase[t] - v;
  int d = (b << 8) + t;
  if (d < n) row_ptr[d] = S + excl;
  if (b == nbk - 1 && t == 0) row_ptr[n] = E;
  dcnt[t] = 0;  // reuse as per-dst cursor
  dexcl[t] = excl;
  __syncthreads();
  for (int i = t; i < cnt; i += 256) {
    int2 e = eds[i];
    int dl = e.y & 255;
    int off = atomicAdd(&dcnt[dl], 1);
    col[S + dexcl[dl] + off] = e.x;
  }
}

// ---------------- BN stats (vectorized, slice writes) + finalize ----------
__global__ __launch_bounds__(256) void bn_stats(const float* __restrict__ h,
                                                float* __restrict__ stats, int n) {
  __shared__ float ssum[64], ssq[64];
  int t = threadIdx.x;
  if (t < 64) { ssum[t] = 0.f; ssq[t] = 0.f; }
  __syncthreads();
  const float4* h4 = (const float4*)h;
  size_t total4 = (size_t)n * 16;
  size_t stride = (size_t)gridDim.x * blockDim.x;   // multiple of 16
  int cbase = ((int)(((size_t)blockIdx.x * blockDim.x + t) & 15)) * 4;
  float s0 = 0.f, s1 = 0.f, s2 = 0.f, s3 = 0.f;
  float q0 = 0.f, q1 = 0.f, q2 = 0.f, q3 = 0.f;
  for (size_t i = (size_t)blockIdx.x * blockDim.x + t; i < total4; i += stride) {
    float4 v = h4[i];
    s0 += v.x; q0 = fmaf(v.x, v.x, q0);
    s1 += v.y; q1 = fmaf(v.y, v.y, q1);
    s2 += v.z; q2 = fmaf(v.z, v.z, q2);
    s3 += v.w; q3 = fmaf(v.w, v.w, q3);
  }
  atomicAdd(&ssum[cbase + 0], s0); atomicAdd(&ssq[cbase + 0], q0);
  atomicAdd(&ssum[cbase + 1], s1); atomicAdd(&ssq[cbase + 1], q1);
  atomicAdd(&ssum[cbase + 2], s2); atomicAdd(&ssq[cbase + 2], q2);
  atomicAdd(&ssum[cbase + 3], s3); atomicAdd(&ssq[cbase + 3], q3);
  __syncthreads();
  if (t < 64) {
    stats[blockIdx.x * 128 + t] = ssum[t];
    stats[blockIdx.x * 128 + 64 + t] = ssq[t];
  }
}

// reduce NSL slices -> scsh (scale/shift). 128 threads: t<64 sums, else sumsq.
__global__ void bn_finalize(const float* __restrict__ stats, const float* __restrict__ g,
                            const float* __restrict__ be, float* __restrict__ scsh,
                            float inv_n) {
  __shared__ float red[128];
  int t = threadIdx.x;  // 128
  int c = t & 63;
  int off = (t >> 6) * 64;  // 0 = sum, 64 = sumsq
  float acc = 0.f;
  for (int b = 0; b < NSL; b++) acc += stats[b * 128 + off + c];
  red[t] = acc;
  __syncthreads();
  if (t < 64) {
    float mean = red[t] * inv_n;
    float var = red[64 + t] * inv_n - mean * mean;
    float sc = rsqrtf(var + 1e-5f) * g[t];
    scsh[t] = sc;
    scsh[64 + t] = be[t] - mean * sc;
  }
}

// ---------------- GAT projection: MFMA fp16, 64 nodes x 128 cols ------------
// h = act @ W on the matrix pipe. 4 waves; wave w owns node rows w*16..+15,
// all 8 col-tiles. A[64][KP] and W^T[128][KP] staged fp16 in LDS, KP = KE+8
// (odd 16B stride -> conflict-free ds_read_b128 fragments). K=16 zero-padded
// to KE=32. C/D layout (m89): col=lane&15, row=(lane>>4)*4+reg.
template <int K, bool BN>
__global__ __launch_bounds__(256) void gat_project_mfma(
    const float* __restrict__ act, const float* __restrict__ scsh,
    const float* __restrict__ W,
    const float* __restrict__ att_s, const float* __restrict__ att_d,
    __half2* __restrict__ hb, float* __restrict__ as_,
    float* __restrict__ ad_, int n) {
  constexpr int KE = (K < 32) ? 32 : K;   // effective (padded) K
  constexpr int KP = KE + 8;              // LDS stride in halves
  constexpr int STAGE = 64 * KP * 2 + 128 * KP * 2;
  constexpr int HSZ = 64 * 136 * 2;
  constexpr int LDSZ = (STAGE > HSZ) ? STAGE : HSZ;
  __shared__ __align__(16) char ldsb[LDSZ];
  __shared__ float attS[256];
  __half* aH = (__half*)ldsb;                      // [64][KP]
  __half* wT = (__half*)(ldsb + 64 * KP * 2);      // [128][KP] (transposed W)
  __half* hS = (__half*)ldsb;                      // [64][136], aliases after barrier

  int t = threadIdx.x;
  int node0 = blockIdx.x * 64;
  int rows = min(64, n - node0);

  // ---- stage A: fp32 -> fp16, BN+ReLU fused; zero-pad r>=rows and k>=K
  constexpr int ACH = 64 * KE / 4;
  for (int i = t; i < ACH; i += 256) {
    int r = i / (KE / 4), kc = i % (KE / 4);
    float4 v = make_float4(0.f, 0.f, 0.f, 0.f);
    if (r < rows && kc * 4 < K)
      v = *(const float4*)&act[(size_t)(node0 + r) * K + kc * 4];
    if (BN) {
      float4 sc4 = *(const float4*)&scsh[kc * 4];
      float4 sh4 = *(const float4*)&scsh[64 + kc * 4];
      v.x = fmaxf(fmaf(v.x, sc4.x, sh4.x), 0.f);
      v.y = fmaxf(fmaf(v.y, sc4.y, sh4.y), 0.f);
      v.z = fmaxf(fmaf(v.z, sc4.z, sh4.z), 0.f);
      v.w = fmaxf(fmaf(v.w, sc4.w, sh4.w), 0.f);
    }
    __half2 h01 = __floats2half2_rn(v.x, v.y);
    __half2 h23 = __floats2half2_rn(v.z, v.w);
    uint2 pk = make_uint2(__builtin_bit_cast(unsigned, h01),
                          __builtin_bit_cast(unsigned, h23));
    *(uint2*)&aH[r * KP + kc * 4] = pk;
  }
  // ---- stage W^T: wT[c][k] fp16 (coalesced global read)
  for (int i = t; i < KE * 128; i += 256) {
    int k = i >> 7, c = i & 127;
    float wv = (k < K) ? W[k * 128 + c] : 0.f;
    wT[c * KP + k] = __float2half(wv);
  }
  attS[t] = (t < 128) ? att_s[t] : att_d[t - 128];
  __syncthreads();

  int w = t >> 6, l = t & 63;
  int cl = l & 15, r4 = l >> 4;
  int w16 = w * 16;

  f32x4 acc[8] = {};
#pragma unroll
  for (int ks = 0; ks < KE / 32; ks++) {
    f16x8 av = *(const f16x8*)&aH[(w16 + cl) * KP + ks * 32 + r4 * 8];
#pragma unroll
    for (int ct = 0; ct < 8; ct++) {
      f16x8 bv = *(const f16x8*)&wT[(ct * 16 + cl) * KP + ks * 32 + r4 * 8];
      acc[ct] = __builtin_amdgcn_mfma_f32_16x16x32_f16(av, bv, acc[ct], 0, 0, 0);
    }
  }

  // ---- att scores from accumulators (per-row dot with att vectors)
  float ats[8], atd[8];
#pragma unroll
  for (int ct = 0; ct < 8; ct++) {
    ats[ct] = attS[ct * 16 + cl];
    atd[ct] = attS[128 + ct * 16 + cl];
  }
#pragma unroll
  for (int i = 0; i < 4; i++) {
    float s0 = 0.f, s1 = 0.f, d0 = 0.f, d1 = 0.f;
#pragma unroll
    for (int ct = 0; ct < 4; ct++) {
      s0 = fmaf(acc[ct][i], ats[ct], s0);
      d0 = fmaf(acc[ct][i], atd[ct], d0);
      s1 = fmaf(acc[ct + 4][i], ats[ct + 4], s1);
      d1 = fmaf(acc[ct + 4][i], atd[ct + 4], d1);
    }
#pragma unroll
    for (int off = 1; off < 16; off <<= 1) {
      s0 += __shfl_xor(s0, off); s1 += __shfl_xor(s1, off);
      d0 += __shfl_xor(d0, off); d1 += __shfl_xor(d1, off);
    }
    int rloc = w16 + r4 * 4 + i;
    if (rloc < rows) {
      int row = node0 + rloc;
      if (cl == 0) as_[row * 2] = s0;
      else if (cl == 1) as_[row * 2 + 1] = s1;
      else if (cl == 2) ad_[row * 2] = d0;
      else if (cl == 3) ad_[row * 2 + 1] = d1;
    }
  }

  __syncthreads();  // aH/wT dead -> reuse as hS
  // ---- C fragments -> hS fp16 [64][136]
#pragma unroll
  for (int ct = 0; ct < 8; ct++)
#pragma unroll
    for (int i = 0; i < 4; i++)
      hS[(w16 + r4 * 4 + i) * 136 + ct * 16 + cl] = __float2half(acc[ct][i]);
  __syncthreads();
  // ---- hS -> hb, coalesced 16B chunks (256B per node row)
#pragma unroll
  for (int it = 0; it < 4; it++) {
    int flat = t + it * 256;
    int nd = flat >> 4, ch = flat & 15;
    if (nd < rows)
      *(uint4*)((char*)hb + (((size_t)(node0 + nd)) << 8) + (ch << 4)) =
          *(const uint4*)((const char*)hS + nd * 272 + (ch << 4));
  }
}

// ---------------- GAT aggregation: 16 lanes/node, 4 nodes/wave (R24) --------
// Natural node order (R28: degree-rank perm cost more locality than its
// balance bought). Lane q accumulates its 8 channels of head (q>=8) over ALL
// edges; 4-deep unroll = 4 independent 256B hb rows in flight per group;
// redundant per-lane den; 9-op head-swap epilogue; NT out stores.
__device__ __forceinline__ void fma8(float* a, float my, uint4 raw) {
  float2 f;
  f = __half22float2(__builtin_bit_cast(__half2, raw.x)); a[0] = fmaf(my, f.x, a[0]); a[1] = fmaf(my, f.y, a[1]);
  f = __half22float2(__builtin_bit_cast(__half2, raw.y)); a[2] = fmaf(my, f.x, a[2]); a[3] = fmaf(my, f.y, a[3]);
  f = __half22float2(__builtin_bit_cast(__half2, raw.z)); a[4] = fmaf(my, f.x, a[4]); a[5] = fmaf(my, f.y, a[5]);
  f = __half22float2(__builtin_bit_cast(__half2, raw.w)); a[6] = fmaf(my, f.x, a[6]); a[7] = fmaf(my, f.y, a[7]);
}

__global__ __launch_bounds__(256) void gat_aggregate(
    const __half2* __restrict__ hb,
    const float* __restrict__ as_, const float* __restrict__ ad_,
    const int* __restrict__ row_ptr, const int* __restrict__ col,
    const float* __restrict__ bias, float* __restrict__ out, int n) {
  int w = (int)((blockIdx.x * blockDim.x + threadIdx.x) >> 6);
  int lane = threadIdx.x & 63;
  int g = lane >> 4, q = lane & 15;
  int d = w * 4 + g;
  if (d >= n) return;  // diverges only in the last wave
  int hidx = (q >= 8) ? 1 : 0;
  int beg = row_ptr[d], end = row_ptr[d + 1];
  const uint4* hb4 = (const uint4*)hb;   // 16 uint4 per node (256 B)

  float ad_my = ad_[d * 2 + hidx];

  float a[8] = {};
  // self-loop (not in CSR)
  float asv = as_[d * 2 + hidx];
  float my = __expf(leaky(asv + ad_my));
  uint4 raw = hb4[(size_t)d * 16 + q];
  fma8(a, my, raw);
  float dpart = my;

  int k = beg;
  for (; k + 3 < end; k += 4) {
    int s0 = col[k], s1 = col[k + 1], s2 = col[k + 2], s3 = col[k + 3];
    float e0 = as_[s0 * 2 + hidx];
    float e1 = as_[s1 * 2 + hidx];
    float e2 = as_[s2 * 2 + hidx];
    float e3 = as_[s3 * 2 + hidx];
    uint4 r0 = hb4[(size_t)s0 * 16 + q];
    uint4 r1 = hb4[(size_t)s1 * 16 + q];
    uint4 r2 = hb4[(size_t)s2 * 16 + q];
    uint4 r3 = hb4[(size_t)s3 * 16 + q];
    float m0 = __expf(leaky(e0 + ad_my));
    float m1 = __expf(leaky(e1 + ad_my));
    float m2 = __expf(leaky(e2 + ad_my));
    float m3 = __expf(leaky(e3 + ad_my));
    fma8(a, m0, r0); fma8(a, m1, r1); fma8(a, m2, r2); fma8(a, m3, r3);
    dpart += m0 + m1 + m2 + m3;
  }
  for (; k < end; k++) {  // tail 0..3
    int s = col[k];
    float e = as_[s * 2 + hidx];
    uint4 r = hb4[(size_t)s * 16 + q];
    float m = __expf(leaky(e + ad_my));
    fma8(a, m, r);
    dpart += m;
  }

  // head swap within the 16-lane group (serves all 4 nodes of the wave)
  float b[8];
#pragma unroll
  for (int i = 0; i < 8; i++) b[i] = __shfl_xor(a[i], 8);
  float denO = __shfl_xor(dpart, 8);

  if (q < 8) {  // channels 8q..8q+7
    float rr0 = 1.f / (dpart + 1e-16f), rr1 = 1.f / (denO + 1e-16f);
    float4 bl = *(const float4*)&bias[q * 8];
    float4 bh = *(const float4*)&bias[q * 8 + 4];
    f32x4 o0, o1;
    o0.x = 0.5f * (a[0] * rr0 + b[0] * rr1) + bl.x;
    o0.y = 0.5f * (a[1] * rr0 + b[1] * rr1) + bl.y;
    o0.z = 0.5f * (a[2] * rr0 + b[2] * rr1) + bl.z;
    o0.w = 0.5f * (a[3] * rr0 + b[3] * rr1) + bl.w;
    o1.x = 0.5f * (a[4] * rr0 + b[4] * rr1) + bh.x;
    o1.y = 0.5f * (a[5] * rr0 + b[5] * rr1) + bh.y;
    o1.z = 0.5f * (a[6] * rr0 + b[6] * rr1) + bh.z;
    o1.w = 0.5f * (a[7] * rr0 + b[7] * rr1) + bh.w;
    f32x4* outp = (f32x4*)&out[(size_t)d * 64 + q * 8];
    __builtin_nontemporal_store(o0, outp);
    __builtin_nontemporal_store(o1, outp + 1);
  }
}

// ---------------- MLP head: fused tiled GEMM (64 nodes / block) --------------
// a1 staging applies BN(layer3 scsh)+ReLU to the raw aggregate output.
// LDS 37.1 KB (was 54.5): GEMM1 output written IN-PLACE over a1 (held in
// registers across a barrier), w2 staged over w1 -> 4 blocks/CU (was 2).
__global__ __launch_bounds__(256) void mlp_head_tiled(
    const float* __restrict__ h3raw, const float* __restrict__ scsh,
    const float* __restrict__ x,
    const float* __restrict__ mW1, const float* __restrict__ mb1,
    const float* __restrict__ mW2, const float* __restrict__ mb2,
    const float* __restrict__ pW, const float* __restrict__ pb,
    const float* __restrict__ vW, const float* __restrict__ vb,
    float* __restrict__ out, int n) {
  __shared__ float lds[9280];
  float* a1  = lds;           // 64*68 = 4352; GEMM1 input, then GEMM1 output
  float* ctx = lds + 4352;    // 64*8  = 512
  float* w1  = lds + 4864;    // 69*64 = 4416; then w2 (64*64 = 4096)

  int t = threadIdx.x;
  int node0 = blockIdx.x * 64;
  int rows = min(64, n - node0);

#pragma unroll
  for (int i = 0; i < 4; i++) {
    int flat = t + i * 256;
    int r = flat >> 4, kc = flat & 15;
    float4 v = make_float4(0.f, 0.f, 0.f, 0.f);
    if (r < rows) v = *(const float4*)&h3raw[(size_t)(node0 + r) * 64 + kc * 4];
    float4 sc4 = *(const float4*)&scsh[kc * 4];
    float4 sh4 = *(const float4*)&scsh[64 + kc * 4];
    v.x = fmaxf(fmaf(v.x, sc4.x, sh4.x), 0.f);
    v.y = fmaxf(fmaf(v.y, sc4.y, sh4.y), 0.f);
    v.z = fmaxf(fmaf(v.z, sc4.z, sh4.z), 0.f);
    v.w = fmaxf(fmaf(v.w, sc4.w, sh4.w), 0.f);
    *(float4*)&a1[r * 68 + kc * 4] = v;
  }
  for (int i = t; i < 320; i += 256) {
    int r = i / 5, j = i % 5;
    ctx[r * 8 + j] = (r < rows) ? x[(size_t)(node0 + r) * 16 + 9 + j] : 0.f;
  }
#pragma unroll
  for (int i = 0; i < 5; i++) {
    int flat = t + i * 256;
    if (flat < 1104) *(float4*)&w1[flat * 4] = *(const float4*)&mW1[flat * 4];
  }
  __syncthreads();

  int tc = t & 15, tr = t >> 4;
  int c0 = tc * 4, r0 = tr * 4;

  float acc[4][4] = {};
  for (int k = 0; k < 64; k += 4) {
    float4 av[4], wv[4];
#pragma unroll
    for (int i = 0; i < 4; i++) av[i] = *(const float4*)&a1[(r0 + i) * 68 + k];
#pragma unroll
    for (int j = 0; j < 4; j++) wv[j] = *(const float4*)&w1[(k + j) * 64 + c0];
#pragma unroll
    for (int i = 0; i < 4; i++) {
      const float* ai = (const float*)&av[i];
#pragma unroll
      for (int kk = 0; kk < 4; kk++) {
        const float* wr = (const float*)&wv[kk];
        acc[i][0] = fmaf(ai[kk], wr[0], acc[i][0]);
        acc[i][1] = fmaf(ai[kk], wr[1], acc[i][1]);
        acc[i][2] = fmaf(ai[kk], wr[2], acc[i][2]);
        acc[i][3] = fmaf(ai[kk], wr[3], acc[i][3]);
      }
    }
  }
#pragma unroll
  for (int k = 64; k < 69; k++) {
    float4 wv = *(const float4*)&w1[k * 64 + c0];
    const float* wr = (const float*)&wv;
#pragma unroll
    for (int i = 0; i < 4; i++) {
      float a = ctx[(r0 + i) * 8 + (k - 64)];
      acc[i][0] = fmaf(a, wr[0], acc[i][0]);
      acc[i][1] = fmaf(a, wr[1], acc[i][1]);
      acc[i][2] = fmaf(a, wr[2], acc[i][2]);
      acc[i][3] = fmaf(a, wr[3], acc[i][3]);
    }
  }
  float b1v0 = mb1[c0], b1v1 = mb1[c0 + 1], b1v2 = mb1[c0 + 2], b1v3 = mb1[c0 + 3];
  float4 t1v[4];
#pragma unroll
  for (int i = 0; i < 4; i++) {
    t1v[i].x = fmaxf(acc[i][0] + b1v0, 0.f);
    t1v[i].y = fmaxf(acc[i][1] + b1v1, 0.f);
    t1v[i].z = fmaxf(acc[i][2] + b1v2, 0.f);
    t1v[i].w = fmaxf(acc[i][3] + b1v3, 0.f);
  }
  __syncthreads();  // all GEMM1 reads of a1/w1 done -> regions reusable

  // GEMM1 output in-place over a1; w2 over w1
#pragma unroll
  for (int i = 0; i < 4; i++)
    *(float4*)&a1[(r0 + i) * 68 + c0] = t1v[i];
#pragma unroll
  for (int i = 0; i < 4; i++) {
    int flat = t + i * 256;
    *(float4*)&w1[flat * 4] = *(const float4*)&mW2[flat * 4];
  }
  __syncthreads();

  float acc2[4][4] = {};
  for (int k = 0; k < 64; k += 4) {
    float4 av[4], wv[4];
#pragma unroll
    for (int i = 0; i < 4; i++) av[i] = *(const float4*)&a1[(r0 + i) * 68 + k];
#pragma unroll
    for (int j = 0; j < 4; j++) wv[j] = *(const float4*)&w1[(k + j) * 64 + c0];
#pragma unroll
    for (int i = 0; i < 4; i++) {
      const float* ai = (const float*)&av[i];
#pragma unroll
      for (int kk = 0; kk < 4; kk++) {
        const float* wr = (const float*)&wv[kk];
        acc2[i][0] = fmaf(ai[kk], wr[0], acc2[i][0]);
        acc2[i][1] = fmaf(ai[kk], wr[1], acc2[i][1]);
        acc2[i][2] = fmaf(ai[kk], wr[2], acc2[i][2]);
        acc2[i][3] = fmaf(ai[kk], wr[3], acc2[i][3]);
      }
    }
  }

  float b2v[4], pwv[4], vwv[4];
#pragma unroll
  for (int j = 0; j < 4; j++) {
    b2v[j] = mb2[c0 + j];
    pwv[j] = pW[c0 + j];
    vwv[j] = vW[c0 + j];
  }
  float p[4], v[4];
#pragma unroll
  for (int i = 0; i < 4; i++) {
    float ps = 0.f, vs = 0.f;
#pragma unroll
    for (int j = 0; j < 4; j++) {
      float u = acc2[i][j] + b2v[j];
      ps = fmaf(u, pwv[j], ps);
      vs = fmaf(u, vwv[j], vs);
    }
    p[i] = ps; v[i] = vs;
  }
#pragma unroll
  for (int off = 1; off < 16; off <<= 1) {
#pragma unroll
    for (int i = 0; i < 4; i++) {
      p[i] += __shfl_xor(p[i], off);
      v[i] += __shfl_xor(v[i], off);
    }
  }
  if (tc == 0) {
    float pbs = pb[0], vbs = vb[0];
#pragma unroll
    for (int i = 0; i < 4; i++) {
      int r = r0 + i;
      if (r < rows) {
        out[node0 + r] = p[i] + pbs;
        out[n + node0 + r] = v[i] + vbs;
      }
    }
  }
}

extern "C" void kernel_launch(void* const* d_in, const int* in_sizes, int n_in,
                              void* d_out, int out_size, void* d_ws, size_t ws_size,
                              hipStream_t stream) {
  const float* x = (const float*)d_in[0];
  const int* ei = (const int*)d_in[1];
  const float* W[3]  = {(const float*)d_in[2],  (const float*)d_in[8],  (const float*)d_in[14]};
  const float* AS[3] = {(const float*)d_in[3],  (const float*)d_in[9],  (const float*)d_in[15]};
  const float* AD[3] = {(const float*)d_in[4],  (const float*)d_in[10], (const float*)d_in[16]};
  const float* B[3]  = {(const float*)d_in[5],  (const float*)d_in[11], (const float*)d_in[17]};
  const float* G[3]  = {(const float*)d_in[6],  (const float*)d_in[12], (const float*)d_in[18]};
  const float* BE[3] = {(const float*)d_in[7],  (const float*)d_in[13], (const float*)d_in[19]};
  const float* mW1 = (const float*)d_in[20];
  const float* mb1 = (const float*)d_in[21];
  const float* mW2 = (const float*)d_in[22];
  const float* mb2 = (const float*)d_in[23];
  const float* pW  = (const float*)d_in[24];
  const float* pb  = (const float*)d_in[25];
  const float* vW  = (const float*)d_in[26];
  const float* vb  = (const float*)d_in[27];

  const int N = in_sizes[0] / 16;
  const int E = in_sizes[1] / 2;
  const int* srcp = ei;
  const int* dstp = ei + E;

  // workspace carve-up (~65 MB)
  float* bufB  = (float*)d_ws;               // N*64  raw aggregate output
  float* hbuf  = bufB + (size_t)N * 64;      // N*64 half2 region (N*64 f32 bytes)
  float* as_   = hbuf + (size_t)N * 64;      // N*2
  float* ad_   = as_ + (size_t)N * 2;        // N*2
  float* stats = ad_ + (size_t)N * 2;        // NSL*128
  float* scsh  = stats + NSL * 128;          // 128
  int* row_ptr = (int*)(scsh + 128);         // N+1
  int* bcnt    = row_ptr + (N + 1);          // 512
  int* boff    = bcnt + 512;                 // 512
  int* bcur    = boff + 512;                 // 512
  int* col     = bcur + 512;                 // E ints (sorted CSR, src only)
  int2* ebuf   = (int2*)(col + E);           // E int2 (staging)
  __half2* hb  = (__half2*)hbuf;

  const int nbk = (N + 255) >> 8;
  const float inv_n = 1.0f / (float)N;

  // ---- CSR build: binned counting sort (R17 formulation)
  hipMemsetAsync(bcnt, 0, sizeof(int) * 512, stream);
  bucket_hist<<<256, 256, 0, stream>>>(dstp, bcnt, E);
  bucket_scan<<<1, 512, 0, stream>>>(bcnt, boff, bcur, nbk);
  bin_scatter<<<(E + 8191) / 8192, 256, 0, stream>>>(srcp, dstp, bcur, ebuf, E);
  bucket_sort<<<nbk, 256, 0, stream>>>(ebuf, boff, col, row_ptr, E, N, nbk);

  const int tiles = (N + 63) / 64;
  const int agg_blocks = (N + 15) / 16;  // 4 nodes/wave, 4 waves/block

  // ---- 3 GAT layers (BN+ReLU fused into the next consumer via scsh)
  for (int l = 0; l < 3; l++) {
    if (l == 0)
      gat_project_mfma<16, false><<<tiles, 256, 0, stream>>>(x, scsh, W[l], AS[l], AD[l],
                                                             hb, as_, ad_, N);
    else
      gat_project_mfma<64, true><<<tiles, 256, 0, stream>>>(bufB, scsh, W[l], AS[l], AD[l],
                                                            hb, as_, ad_, N);
    gat_aggregate<<<agg_blocks, 256, 0, stream>>>(hb, as_, ad_, row_ptr, col,
                                                  B[l], bufB, N);
    bn_stats<<<NSL, 256, 0, stream>>>(bufB, stats, N);
    bn_finalize<<<1, 128, 0, stream>>>(stats, G[l], BE[l], scsh, inv_n);
  }

  // ---- MLP head -> (logits, value); applies layer-3 BN+ReLU to bufB
  mlp_head_tiled<<<tiles, 256, 0, stream>>>(bufB, scsh, x, mW1, mb1, mW2, mb2,
                                            pW, pb, vW, vb, (float*)d_out, N);
}

// Round 12
// 454.702 us; speedup vs baseline: 1.3605x; 1.0195x over previous
//
#include <hip/hip_runtime.h>
#include <hip/hip_fp16.h>

// N=100000 nodes, E=1000000 edges, D_IN=16, H=2, C=64.
// 3x (GAT -> BN -> ReLU), then MLP head -> (logits, value) concat in d_out.
// R30 = R29 (463.5us best) + W-transpose hoisted out of the projection.
// R29's projection re-transposed W to fp16 in EVERY block (1563x): 32
// scalar-load iterations + 2B LDS stores at bank-stride-4 (8-way conflict)
// before any MFMA could issue. Now one tiny upfront kernel (transpose_ws)
// builds fp16 W^T once per layer in global (wTg, 40KB total); projection
// stages it with 4 coalesced uint4 iterations, conflict-free, same padded
// LDS layout (fragment reads unchanged; numerics identical).
// Kept: R26 MFMA fp16 projection, R24 aggregate (16 lanes/node, 4 nodes/
// wave, 4-deep, natural order — R28 perm regressed), NT out stores, R29 slim
// mlp (37KB LDS, 4 blocks/CU), R17 CSR build, slice-write bn_stats +
// separate bn_finalize (fence/atomic fusions proven losers on 8-XCD),
// scsh BN fusion into consumers.

__device__ __forceinline__ float leaky(float x) { return x > 0.f ? x : 0.2f * x; }

typedef float f32x4 __attribute__((ext_vector_type(4)));
typedef _Float16 f16x8 __attribute__((ext_vector_type(8)));

#define BCAP 4096  // max edges per 256-dst bucket (mean ~2560)
#define NSL 256    // bn_stats slices

// ---------------- CSR build ----------------
__global__ void bucket_hist(const int* __restrict__ dst, int* __restrict__ bcnt, int E) {
  __shared__ int cnt[512];
  int t = threadIdx.x;
  cnt[t] = 0; cnt[t + 256] = 0;
  __syncthreads();
  for (int e = blockIdx.x * blockDim.x + t; e < E; e += gridDim.x * blockDim.x)
    atomicAdd(&cnt[dst[e] >> 8], 1);
  __syncthreads();
  for (int i = t; i < 512; i += 256)
    if (cnt[i]) atomicAdd(&bcnt[i], cnt[i]);
}

__global__ void bucket_scan(const int* __restrict__ bcnt, int* __restrict__ boff,
                            int* __restrict__ bcur, int nbk) {
  __shared__ int temp[512];
  int t = threadIdx.x;  // 512 threads
  int v = (t < nbk) ? bcnt[t] : 0;
  temp[t] = v;
  __syncthreads();
  for (int off = 1; off < 512; off <<= 1) {
    int add = (t >= off) ? temp[t - off] : 0;
    __syncthreads();
    temp[t] += add;
    __syncthreads();
  }
  if (t < nbk) {
    int ex = temp[t] - v;
    boff[t] = ex;
    bcur[t] = ex;
  }
}

__global__ __launch_bounds__(256) void bin_scatter(
    const int* __restrict__ src, const int* __restrict__ dst,
    int* __restrict__ bcur, int2* __restrict__ ebuf, int E) {
  __shared__ int cnt[512];
  __shared__ int base[512];
  int t = threadIdx.x;
  int beg = blockIdx.x * 8192;
  int end = min(E, beg + 8192);
  cnt[t] = 0; cnt[t + 256] = 0;
  __syncthreads();
  for (int e = beg + t; e < end; e += 256)
    atomicAdd(&cnt[dst[e] >> 8], 1);
  __syncthreads();
  for (int i = t; i < 512; i += 256) {
    base[i] = cnt[i] ? atomicAdd(&bcur[i], cnt[i]) : 0;
    cnt[i] = 0;  // reuse as within-run cursor
  }
  __syncthreads();
  for (int e = beg + t; e < end; e += 256) {
    int d = dst[e];
    int bk = d >> 8;
    int off = atomicAdd(&cnt[bk], 1);
    ebuf[base[bk] + off] = make_int2(src[e], d);
  }
}

__global__ __launch_bounds__(256) void bucket_sort(
    const int2* __restrict__ ebuf, const int* __restrict__ boff,
    int* __restrict__ col, int* __restrict__ row_ptr, int E, int n, int nbk) {
  __shared__ int2 eds[BCAP];
  __shared__ int dcnt[256];
  __shared__ int dbase[256];
  __shared__ int dexcl[256];
  int b = blockIdx.x, t = threadIdx.x;
  int S = boff[b];
  int Eend = (b + 1 < nbk) ? boff[b + 1] : E;
  int cnt = min(Eend - S, BCAP);
  for (int i = t; i < cnt; i += 256) eds[i] = ebuf[S + i];
  dcnt[t] = 0;
  __syncthreads();
  for (int i = t; i < cnt; i += 256) atomicAdd(&dcnt[eds[i].y & 255], 1);
  __syncthreads();
  int v = dcnt[t];
  dbase[t] = v;
  __syncthreads();
  for (int off = 1; off < 256; off <<= 1) {
    int add = (t >= off) ? dbase[t - off] : 0;
    __syncthreads();
    dbase[t] += add;
    __syncthreads();
  }
  int excl = dbase[t] - v;
  int d = (b << 8) + t;
  if (d < n) row_ptr[d] = S + excl;
  if (b == nbk - 1 && t == 0) row_ptr[n] = E;
  dcnt[t] = 0;  // reuse as per-dst cursor
  dexcl[t] = excl;
  __syncthreads();
  for (int i = t; i < cnt; i += 256) {
    int2 e = eds[i];
    int dl = e.y & 255;
    int off = atomicAdd(&dcnt[dl], 1);
    col[S + dexcl[dl] + off] = e.x;
  }
}

// ---------------- W transpose: once per layer, fp32 [K][128] -> fp16 [128][KE]
// Layer 0: K=16, KE=32 (zero-padded), at wTg+0 (4096 halves).
// Layers 1,2: K=KE=64, at wTg+4096 and wTg+12288. grid 80 x 256 = 20480 = total.
__global__ void transpose_ws(const float* __restrict__ W0, const float* __restrict__ W1,
                             const float* __restrict__ W2, __half* __restrict__ wTg) {
  int i = blockIdx.x * 256 + threadIdx.x;
  if (i < 4096) {                      // layer 0: [128][32]
    int c = i >> 5, k = i & 31;
    wTg[i] = __float2half(k < 16 ? W0[k * 128 + c] : 0.f);
  } else if (i < 12288) {              // layer 1: [128][64]
    int j = i - 4096;
    int c = j >> 6, k = j & 63;
    wTg[i] = __float2half(W1[k * 128 + c]);
  } else if (i < 20480) {              // layer 2: [128][64]
    int j = i - 12288;
    int c = j >> 6, k = j & 63;
    wTg[i] = __float2half(W2[k * 128 + c]);
  }
}

// ---------------- BN stats (vectorized, slice writes) + finalize ----------
__global__ __launch_bounds__(256) void bn_stats(const float* __restrict__ h,
                                                float* __restrict__ stats, int n) {
  __shared__ float ssum[64], ssq[64];
  int t = threadIdx.x;
  if (t < 64) { ssum[t] = 0.f; ssq[t] = 0.f; }
  __syncthreads();
  const float4* h4 = (const float4*)h;
  size_t total4 = (size_t)n * 16;
  size_t stride = (size_t)gridDim.x * blockDim.x;   // multiple of 16
  int cbase = ((int)(((size_t)blockIdx.x * blockDim.x + t) & 15)) * 4;
  float s0 = 0.f, s1 = 0.f, s2 = 0.f, s3 = 0.f;
  float q0 = 0.f, q1 = 0.f, q2 = 0.f, q3 = 0.f;
  for (size_t i = (size_t)blockIdx.x * blockDim.x + t; i < total4; i += stride) {
    float4 v = h4[i];
    s0 += v.x; q0 = fmaf(v.x, v.x, q0);
    s1 += v.y; q1 = fmaf(v.y, v.y, q1);
    s2 += v.z; q2 = fmaf(v.z, v.z, q2);
    s3 += v.w; q3 = fmaf(v.w, v.w, q3);
  }
  atomicAdd(&ssum[cbase + 0], s0); atomicAdd(&ssq[cbase + 0], q0);
  atomicAdd(&ssum[cbase + 1], s1); atomicAdd(&ssq[cbase + 1], q1);
  atomicAdd(&ssum[cbase + 2], s2); atomicAdd(&ssq[cbase + 2], q2);
  atomicAdd(&ssum[cbase + 3], s3); atomicAdd(&ssq[cbase + 3], q3);
  __syncthreads();
  if (t < 64) {
    stats[blockIdx.x * 128 + t] = ssum[t];
    stats[blockIdx.x * 128 + 64 + t] = ssq[t];
  }
}

// reduce NSL slices -> scsh (scale/shift). 128 threads: t<64 sums, else sumsq.
__global__ void bn_finalize(const float* __restrict__ stats, const float* __restrict__ g,
                            const float* __restrict__ be, float* __restrict__ scsh,
                            float inv_n) {
  __shared__ float red[128];
  int t = threadIdx.x;  // 128
  int c = t & 63;
  int off = (t >> 6) * 64;  // 0 = sum, 64 = sumsq
  float acc = 0.f;
  for (int b = 0; b < NSL; b++) acc += stats[b * 128 + off + c];
  red[t] = acc;
  __syncthreads();
  if (t < 64) {
    float mean = red[t] * inv_n;
    float var = red[64 + t] * inv_n - mean * mean;
    float sc = rsqrtf(var + 1e-5f) * g[t];
    scsh[t] = sc;
    scsh[64 + t] = be[t] - mean * sc;
  }
}

// ---------------- GAT projection: MFMA fp16, 64 nodes x 128 cols ------------
// h = act @ W on the matrix pipe. 4 waves; wave w owns node rows w*16..+15,
// all 8 col-tiles. A[64][KP] staged fp16 (BN+ReLU fused); W^T comes
// pre-transposed fp16 from wTg (global, L2-resident) via coalesced uint4
// copies into the padded [128][KP] LDS layout. KP = KE+8 (odd 16B stride ->
// conflict-free b128 fragment reads). C/D layout (m89): col=lane&15,
// row=(lane>>4)*4+reg.
template <int K, bool BN>
__global__ __launch_bounds__(256) void gat_project_mfma(
    const float* __restrict__ act, const float* __restrict__ scsh,
    const __half* __restrict__ wTg,
    const float* __restrict__ att_s, const float* __restrict__ att_d,
    __half2* __restrict__ hb, float* __restrict__ as_,
    float* __restrict__ ad_, int n) {
  constexpr int KE = (K < 32) ? 32 : K;   // effective (padded) K
  constexpr int KP = KE + 8;              // LDS stride in halves
  constexpr int STAGE = 64 * KP * 2 + 128 * KP * 2;
  constexpr int HSZ = 64 * 136 * 2;
  constexpr int LDSZ = (STAGE > HSZ) ? STAGE : HSZ;
  __shared__ __align__(16) char ldsb[LDSZ];
  __shared__ float attS[256];
  __half* aH = (__half*)ldsb;                      // [64][KP]
  __half* wT = (__half*)(ldsb + 64 * KP * 2);      // [128][KP] (transposed W)
  __half* hS = (__half*)ldsb;                      // [64][136], aliases after barrier

  int t = threadIdx.x;
  int node0 = blockIdx.x * 64;
  int rows = min(64, n - node0);

  // ---- stage A: fp32 -> fp16, BN+ReLU fused; zero-pad r>=rows and k>=K
  constexpr int ACH = 64 * KE / 4;
  for (int i = t; i < ACH; i += 256) {
    int r = i / (KE / 4), kc = i % (KE / 4);
    float4 v = make_float4(0.f, 0.f, 0.f, 0.f);
    if (r < rows && kc * 4 < K)
      v = *(const float4*)&act[(size_t)(node0 + r) * K + kc * 4];
    if (BN) {
      float4 sc4 = *(const float4*)&scsh[kc * 4];
      float4 sh4 = *(const float4*)&scsh[64 + kc * 4];
      v.x = fmaxf(fmaf(v.x, sc4.x, sh4.x), 0.f);
      v.y = fmaxf(fmaf(v.y, sc4.y, sh4.y), 0.f);
      v.z = fmaxf(fmaf(v.z, sc4.z, sh4.z), 0.f);
      v.w = fmaxf(fmaf(v.w, sc4.w, sh4.w), 0.f);
    }
    __half2 h01 = __floats2half2_rn(v.x, v.y);
    __half2 h23 = __floats2half2_rn(v.z, v.w);
    uint2 pk = make_uint2(__builtin_bit_cast(unsigned, h01),
                          __builtin_bit_cast(unsigned, h23));
    *(uint2*)&aH[r * KP + kc * 4] = pk;
  }
  // ---- stage W^T: coalesced uint4 copy from pre-transposed wTg
  constexpr int WCH = 128 * KE / 8;   // 16B chunks
  for (int i = t; i < WCH; i += 256) {
    int c = i / (KE / 8), j = i % (KE / 8);
    *(uint4*)&wT[c * KP + j * 8] = *(const uint4*)&wTg[c * KE + j * 8];
  }
  attS[t] = (t < 128) ? att_s[t] : att_d[t - 128];
  __syncthreads();

  int w = t >> 6, l = t & 63;
  int cl = l & 15, r4 = l >> 4;
  int w16 = w * 16;

  f32x4 acc[8] = {};
#pragma unroll
  for (int ks = 0; ks < KE / 32; ks++) {
    f16x8 av = *(const f16x8*)&aH[(w16 + cl) * KP + ks * 32 + r4 * 8];
#pragma unroll
    for (int ct = 0; ct < 8; ct++) {
      f16x8 bv = *(const f16x8*)&wT[(ct * 16 + cl) * KP + ks * 32 + r4 * 8];
      acc[ct] = __builtin_amdgcn_mfma_f32_16x16x32_f16(av, bv, acc[ct], 0, 0, 0);
    }
  }

  // ---- att scores from accumulators (per-row dot with att vectors)
  float ats[8], atd[8];
#pragma unroll
  for (int ct = 0; ct < 8; ct++) {
    ats[ct] = attS[ct * 16 + cl];
    atd[ct] = attS[128 + ct * 16 + cl];
  }
#pragma unroll
  for (int i = 0; i < 4; i++) {
    float s0 = 0.f, s1 = 0.f, d0 = 0.f, d1 = 0.f;
#pragma unroll
    for (int ct = 0; ct < 4; ct++) {
      s0 = fmaf(acc[ct][i], ats[ct], s0);
      d0 = fmaf(acc[ct][i], atd[ct], d0);
      s1 = fmaf(acc[ct + 4][i], ats[ct + 4], s1);
      d1 = fmaf(acc[ct + 4][i], atd[ct + 4], d1);
    }
#pragma unroll
    for (int off = 1; off < 16; off <<= 1) {
      s0 += __shfl_xor(s0, off); s1 += __shfl_xor(s1, off);
      d0 += __shfl_xor(d0, off); d1 += __shfl_xor(d1, off);
    }
    int rloc = w16 + r4 * 4 + i;
    if (rloc < rows) {
      int row = node0 + rloc;
      if (cl == 0) as_[row * 2] = s0;
      else if (cl == 1) as_[row * 2 + 1] = s1;
      else if (cl == 2) ad_[row * 2] = d0;
      else if (cl == 3) ad_[row * 2 + 1] = d1;
    }
  }

  __syncthreads();  // aH/wT dead -> reuse as hS
  // ---- C fragments -> hS fp16 [64][136]
#pragma unroll
  for (int ct = 0; ct < 8; ct++)
#pragma unroll
    for (int i = 0; i < 4; i++)
      hS[(w16 + r4 * 4 + i) * 136 + ct * 16 + cl] = __float2half(acc[ct][i]);
  __syncthreads();
  // ---- hS -> hb, coalesced 16B chunks (256B per node row)
#pragma unroll
  for (int it = 0; it < 4; it++) {
    int flat = t + it * 256;
    int nd = flat >> 4, ch = flat & 15;
    if (nd < rows)
      *(uint4*)((char*)hb + (((size_t)(node0 + nd)) << 8) + (ch << 4)) =
          *(const uint4*)((const char*)hS + nd * 272 + (ch << 4));
  }
}

// ---------------- GAT aggregation: 16 lanes/node, 4 nodes/wave (R24) --------
// Natural node order (R28: degree-rank perm cost more locality than its
// balance bought). Lane q accumulates its 8 channels of head (q>=8) over ALL
// edges; 4-deep unroll = 4 independent 256B hb rows in flight per group;
// redundant per-lane den; 9-op head-swap epilogue; NT out stores.
__device__ __forceinline__ void fma8(float* a, float my, uint4 raw) {
  float2 f;
  f = __half22float2(__builtin_bit_cast(__half2, raw.x)); a[0] = fmaf(my, f.x, a[0]); a[1] = fmaf(my, f.y, a[1]);
  f = __half22float2(__builtin_bit_cast(__half2, raw.y)); a[2] = fmaf(my, f.x, a[2]); a[3] = fmaf(my, f.y, a[3]);
  f = __half22float2(__builtin_bit_cast(__half2, raw.z)); a[4] = fmaf(my, f.x, a[4]); a[5] = fmaf(my, f.y, a[5]);
  f = __half22float2(__builtin_bit_cast(__half2, raw.w)); a[6] = fmaf(my, f.x, a[6]); a[7] = fmaf(my, f.y, a[7]);
}

__global__ __launch_bounds__(256) void gat_aggregate(
    const __half2* __restrict__ hb,
    const float* __restrict__ as_, const float* __restrict__ ad_,
    const int* __restrict__ row_ptr, const int* __restrict__ col,
    const float* __restrict__ bias, float* __restrict__ out, int n) {
  int w = (int)((blockIdx.x * blockDim.x + threadIdx.x) >> 6);
  int lane = threadIdx.x & 63;
  int g = lane >> 4, q = lane & 15;
  int d = w * 4 + g;
  if (d >= n) return;  // diverges only in the last wave
  int hidx = (q >= 8) ? 1 : 0;
  int beg = row_ptr[d], end = row_ptr[d + 1];
  const uint4* hb4 = (const uint4*)hb;   // 16 uint4 per node (256 B)

  float ad_my = ad_[d * 2 + hidx];

  float a[8] = {};
  // self-loop (not in CSR)
  float asv = as_[d * 2 + hidx];
  float my = __expf(leaky(asv + ad_my));
  uint4 raw = hb4[(size_t)d * 16 + q];
  fma8(a, my, raw);
  float dpart = my;

  int k = beg;
  for (; k + 3 < end; k += 4) {
    int s0 = col[k], s1 = col[k + 1], s2 = col[k + 2], s3 = col[k + 3];
    float e0 = as_[s0 * 2 + hidx];
    float e1 = as_[s1 * 2 + hidx];
    float e2 = as_[s2 * 2 + hidx];
    float e3 = as_[s3 * 2 + hidx];
    uint4 r0 = hb4[(size_t)s0 * 16 + q];
    uint4 r1 = hb4[(size_t)s1 * 16 + q];
    uint4 r2 = hb4[(size_t)s2 * 16 + q];
    uint4 r3 = hb4[(size_t)s3 * 16 + q];
    float m0 = __expf(leaky(e0 + ad_my));
    float m1 = __expf(leaky(e1 + ad_my));
    float m2 = __expf(leaky(e2 + ad_my));
    float m3 = __expf(leaky(e3 + ad_my));
    fma8(a, m0, r0); fma8(a, m1, r1); fma8(a, m2, r2); fma8(a, m3, r3);
    dpart += m0 + m1 + m2 + m3;
  }
  for (; k < end; k++) {  // tail 0..3
    int s = col[k];
    float e = as_[s * 2 + hidx];
    uint4 r = hb4[(size_t)s * 16 + q];
    float m = __expf(leaky(e + ad_my));
    fma8(a, m, r);
    dpart += m;
  }

  // head swap within the 16-lane group (serves all 4 nodes of the wave)
  float b[8];
#pragma unroll
  for (int i = 0; i < 8; i++) b[i] = __shfl_xor(a[i], 8);
  float denO = __shfl_xor(dpart, 8);

  if (q < 8) {  // channels 8q..8q+7
    float rr0 = 1.f / (dpart + 1e-16f), rr1 = 1.f / (denO + 1e-16f);
    float4 bl = *(const float4*)&bias[q * 8];
    float4 bh = *(const float4*)&bias[q * 8 + 4];
    f32x4 o0, o1;
    o0.x = 0.5f * (a[0] * rr0 + b[0] * rr1) + bl.x;
    o0.y = 0.5f * (a[1] * rr0 + b[1] * rr1) + bl.y;
    o0.z = 0.5f * (a[2] * rr0 + b[2] * rr1) + bl.z;
    o0.w = 0.5f * (a[3] * rr0 + b[3] * rr1) + bl.w;
    o1.x = 0.5f * (a[4] * rr0 + b[4] * rr1) + bh.x;
    o1.y = 0.5f * (a[5] * rr0 + b[5] * rr1) + bh.y;
    o1.z = 0.5f * (a[6] * rr0 + b[6] * rr1) + bh.z;
    o1.w = 0.5f * (a[7] * rr0 + b[7] * rr1) + bh.w;
    f32x4* outp = (f32x4*)&out[(size_t)d * 64 + q * 8];
    __builtin_nontemporal_store(o0, outp);
    __builtin_nontemporal_store(o1, outp + 1);
  }
}

// ---------------- MLP head: fused tiled GEMM (64 nodes / block) --------------
// a1 staging applies BN(layer3 scsh)+ReLU to the raw aggregate output.
// LDS 37.1 KB: GEMM1 output written IN-PLACE over a1 (held in registers
// across a barrier), w2 staged over w1 -> 4 blocks/CU.
__global__ __launch_bounds__(256) void mlp_head_tiled(
    const float* __restrict__ h3raw, const float* __restrict__ scsh,
    const float* __restrict__ x,
    const float* __restrict__ mW1, const float* __restrict__ mb1,
    const float* __restrict__ mW2, const float* __restrict__ mb2,
    const float* __restrict__ pW, const float* __restrict__ pb,
    const float* __restrict__ vW, const float* __restrict__ vb,
    float* __restrict__ out, int n) {
  __shared__ float lds[9280];
  float* a1  = lds;           // 64*68 = 4352; GEMM1 input, then GEMM1 output
  float* ctx = lds + 4352;    // 64*8  = 512
  float* w1  = lds + 4864;    // 69*64 = 4416; then w2 (64*64 = 4096)

  int t = threadIdx.x;
  int node0 = blockIdx.x * 64;
  int rows = min(64, n - node0);

#pragma unroll
  for (int i = 0; i < 4; i++) {
    int flat = t + i * 256;
    int r = flat >> 4, kc = flat & 15;
    float4 v = make_float4(0.f, 0.f, 0.f, 0.f);
    if (r < rows) v = *(const float4*)&h3raw[(size_t)(node0 + r) * 64 + kc * 4];
    float4 sc4 = *(const float4*)&scsh[kc * 4];
    float4 sh4 = *(const float4*)&scsh[64 + kc * 4];
    v.x = fmaxf(fmaf(v.x, sc4.x, sh4.x), 0.f);
    v.y = fmaxf(fmaf(v.y, sc4.y, sh4.y), 0.f);
    v.z = fmaxf(fmaf(v.z, sc4.z, sh4.z), 0.f);
    v.w = fmaxf(fmaf(v.w, sc4.w, sh4.w), 0.f);
    *(float4*)&a1[r * 68 + kc * 4] = v;
  }
  for (int i = t; i < 320; i += 256) {
    int r = i / 5, j = i % 5;
    ctx[r * 8 + j] = (r < rows) ? x[(size_t)(node0 + r) * 16 + 9 + j] : 0.f;
  }
#pragma unroll
  for (int i = 0; i < 5; i++) {
    int flat = t + i * 256;
    if (flat < 1104) *(float4*)&w1[flat * 4] = *(const float4*)&mW1[flat * 4];
  }
  __syncthreads();

  int tc = t & 15, tr = t >> 4;
  int c0 = tc * 4, r0 = tr * 4;

  float acc[4][4] = {};
  for (int k = 0; k < 64; k += 4) {
    float4 av[4], wv[4];
#pragma unroll
    for (int i = 0; i < 4; i++) av[i] = *(const float4*)&a1[(r0 + i) * 68 + k];
#pragma unroll
    for (int j = 0; j < 4; j++) wv[j] = *(const float4*)&w1[(k + j) * 64 + c0];
#pragma unroll
    for (int i = 0; i < 4; i++) {
      const float* ai = (const float*)&av[i];
#pragma unroll
      for (int kk = 0; kk < 4; kk++) {
        const float* wr = (const float*)&wv[kk];
        acc[i][0] = fmaf(ai[kk], wr[0], acc[i][0]);
        acc[i][1] = fmaf(ai[kk], wr[1], acc[i][1]);
        acc[i][2] = fmaf(ai[kk], wr[2], acc[i][2]);
        acc[i][3] = fmaf(ai[kk], wr[3], acc[i][3]);
      }
    }
  }
#pragma unroll
  for (int k = 64; k < 69; k++) {
    float4 wv = *(const float4*)&w1[k * 64 + c0];
    const float* wr = (const float*)&wv;
#pragma unroll
    for (int i = 0; i < 4; i++) {
      float a = ctx[(r0 + i) * 8 + (k - 64)];
      acc[i][0] = fmaf(a, wr[0], acc[i][0]);
      acc[i][1] = fmaf(a, wr[1], acc[i][1]);
      acc[i][2] = fmaf(a, wr[2], acc[i][2]);
      acc[i][3] = fmaf(a, wr[3], acc[i][3]);
    }
  }
  float b1v0 = mb1[c0], b1v1 = mb1[c0 + 1], b1v2 = mb1[c0 + 2], b1v3 = mb1[c0 + 3];
  float4 t1v[4];
#pragma unroll
  for (int i = 0; i < 4; i++) {
    t1v[i].x = fmaxf(acc[i][0] + b1v0, 0.f);
    t1v[i].y = fmaxf(acc[i][1] + b1v1, 0.f);
    t1v[i].z = fmaxf(acc[i][2] + b1v2, 0.f);
    t1v[i].w = fmaxf(acc[i][3] + b1v3, 0.f);
  }
  __syncthreads();  // all GEMM1 reads of a1/w1 done -> regions reusable

  // GEMM1 output in-place over a1; w2 over w1
#pragma unroll
  for (int i = 0; i < 4; i++)
    *(float4*)&a1[(r0 + i) * 68 + c0] = t1v[i];
#pragma unroll
  for (int i = 0; i < 4; i++) {
    int flat = t + i * 256;
    *(float4*)&w1[flat * 4] = *(const float4*)&mW2[flat * 4];
  }
  __syncthreads();

  float acc2[4][4] = {};
  for (int k = 0; k < 64; k += 4) {
    float4 av[4], wv[4];
#pragma unroll
    for (int i = 0; i < 4; i++) av[i] = *(const float4*)&a1[(r0 + i) * 68 + k];
#pragma unroll
    for (int j = 0; j < 4; j++) wv[j] = *(const float4*)&w1[(k + j) * 64 + c0];
#pragma unroll
    for (int i = 0; i < 4; i++) {
      const float* ai = (const float*)&av[i];
#pragma unroll
      for (int kk = 0; kk < 4; kk++) {
        const float* wr = (const float*)&wv[kk];
        acc2[i][0] = fmaf(ai[kk], wr[0], acc2[i][0]);
        acc2[i][1] = fmaf(ai[kk], wr[1], acc2[i][1]);
        acc2[i][2] = fmaf(ai[kk], wr[2], acc2[i][2]);
        acc2[i][3] = fmaf(ai[kk], wr[3], acc2[i][3]);
      }
    }
  }

  float b2v[4], pwv[4], vwv[4];
#pragma unroll
  for (int j = 0; j < 4; j++) {
    b2v[j] = mb2[c0 + j];
    pwv[j] = pW[c0 + j];
    vwv[j] = vW[c0 + j];
  }
  float p[4], v[4];
#pragma unroll
  for (int i = 0; i < 4; i++) {
    float ps = 0.f, vs = 0.f;
#pragma unroll
    for (int j = 0; j < 4; j++) {
      float u = acc2[i][j] + b2v[j];
      ps = fmaf(u, pwv[j], ps);
      vs = fmaf(u, vwv[j], vs);
    }
    p[i] = ps; v[i] = vs;
  }
#pragma unroll
  for (int off = 1; off < 16; off <<= 1) {
#pragma unroll
    for (int i = 0; i < 4; i++) {
      p[i] += __shfl_xor(p[i], off);
      v[i] += __shfl_xor(v[i], off);
    }
  }
  if (tc == 0) {
    float pbs = pb[0], vbs = vb[0];
#pragma unroll
    for (int i = 0; i < 4; i++) {
      int r = r0 + i;
      if (r < rows) {
        out[node0 + r] = p[i] + pbs;
        out[n + node0 + r] = v[i] + vbs;
      }
    }
  }
}

extern "C" void kernel_launch(void* const* d_in, const int* in_sizes, int n_in,
                              void* d_out, int out_size, void* d_ws, size_t ws_size,
                              hipStream_t stream) {
  const float* x = (const float*)d_in[0];
  const int* ei = (const int*)d_in[1];
  const float* W[3]  = {(const float*)d_in[2],  (const float*)d_in[8],  (const float*)d_in[14]};
  const float* AS[3] = {(const float*)d_in[3],  (const float*)d_in[9],  (const float*)d_in[15]};
  const float* AD[3] = {(const float*)d_in[4],  (const float*)d_in[10], (const float*)d_in[16]};
  const float* B[3]  = {(const float*)d_in[5],  (const float*)d_in[11], (const float*)d_in[17]};
  const float* G[3]  = {(const float*)d_in[6],  (const float*)d_in[12], (const float*)d_in[18]};
  const float* BE[3] = {(const float*)d_in[7],  (const float*)d_in[13], (const float*)d_in[19]};
  const float* mW1 = (const float*)d_in[20];
  const float* mb1 = (const float*)d_in[21];
  const float* mW2 = (const float*)d_in[22];
  const float* mb2 = (const float*)d_in[23];
  const float* pW  = (const float*)d_in[24];
  const float* pb  = (const float*)d_in[25];
  const float* vW  = (const float*)d_in[26];
  const float* vb  = (const float*)d_in[27];

  const int N = in_sizes[0] / 16;
  const int E = in_sizes[1] / 2;
  const int* srcp = ei;
  const int* dstp = ei + E;

  // workspace carve-up (~65 MB)
  float* bufB  = (float*)d_ws;               // N*64  raw aggregate output
  float* hbuf  = bufB + (size_t)N * 64;      // N*64 half2 region (N*64 f32 bytes)
  float* as_   = hbuf + (size_t)N * 64;      // N*2
  float* ad_   = as_ + (size_t)N * 2;        // N*2
  float* stats = ad_ + (size_t)N * 2;        // NSL*128
  float* scsh  = stats + NSL * 128;          // 128
  __half* wTg  = (__half*)(scsh + 128);      // 20480 halves (3 transposed W's)
  int* row_ptr = (int*)(wTg + 20480);        // N+1
  int* bcnt    = row_ptr + (N + 1);          // 512
  int* boff    = bcnt + 512;                 // 512
  int* bcur    = boff + 512;                 // 512
  int* col     = bcur + 512;                 // E ints (sorted CSR, src only)
  int2* ebuf   = (int2*)(col + E);           // E int2 (staging)
  __half2* hb  = (__half2*)hbuf;
  const __half* wTgL[3] = {wTg, wTg + 4096, wTg + 12288};

  const int nbk = (N + 255) >> 8;
  const float inv_n = 1.0f / (float)N;

  // ---- W transposes (once) + CSR build: binned counting sort
  transpose_ws<<<80, 256, 0, stream>>>(W[0], W[1], W[2], wTg);
  hipMemsetAsync(bcnt, 0, sizeof(int) * 512, stream);
  bucket_hist<<<256, 256, 0, stream>>>(dstp, bcnt, E);
  bucket_scan<<<1, 512, 0, stream>>>(bcnt, boff, bcur, nbk);
  bin_scatter<<<(E + 8191) / 8192, 256, 0, stream>>>(srcp, dstp, bcur, ebuf, E);
  bucket_sort<<<nbk, 256, 0, stream>>>(ebuf, boff, col, row_ptr, E, N, nbk);

  const int tiles = (N + 63) / 64;
  const int agg_blocks = (N + 15) / 16;  // 4 nodes/wave, 4 waves/block

  // ---- 3 GAT layers (BN+ReLU fused into the next consumer via scsh)
  for (int l = 0; l < 3; l++) {
    if (l == 0)
      gat_project_mfma<16, false><<<tiles, 256, 0, stream>>>(x, scsh, wTgL[l], AS[l], AD[l],
                                                             hb, as_, ad_, N);
    else
      gat_project_mfma<64, true><<<tiles, 256, 0, stream>>>(bufB, scsh, wTgL[l], AS[l], AD[l],
                                                            hb, as_, ad_, N);
    gat_aggregate<<<agg_blocks, 256, 0, stream>>>(hb, as_, ad_, row_ptr, col,
                                                  B[l], bufB, N);
    bn_stats<<<NSL, 256, 0, stream>>>(bufB, stats, N);
    bn_finalize<<<1, 128, 0, stream>>>(stats, G[l], BE[l], scsh, inv_n);
  }

  // ---- MLP head -> (logits, value); applies layer-3 BN+ReLU to bufB
  mlp_head_tiled<<<tiles, 256, 0, stream>>>(bufB, scsh, x, mW1, mb1, mW2, mb2,
                                            pW, pb, vW, vb, (float*)d_out, N);
}

// Round 13
// 452.728 us; speedup vs baseline: 1.3665x; 1.0044x over previous
//
#include <hip/hip_runtime.h>
#include <hip/hip_fp16.h>

// N=100000 nodes, E=1000000 edges, D_IN=16, H=2, C=64.
// 3x (GAT -> BN -> ReLU), then MLP head -> (logits, value) concat in d_out.
// R31 = R30 (454.7us best) + two changes:
// (a) Attention scores computed ON THE MATRIX PIPE: as/ad are linear in A
//     (as = A·(W·att_s)), so transpose_ws precomputes w_as/w_ad per head and
//     the projection carries a 9th 16-wide column tile (cols 128..131).
//     One extra MFMA per k-step replaces the whole score epilogue
//     (attS staging + 64 shfl_xor + 32 fma per wave -> 4 direct lane writes).
// (b) bn_finalize widened to 1024 threads (serial 256-iter strided walk was
//     ~10us as a 1-block kernel; now 32 iters/thread, R22-verified code).
// Kept: R26/R30 MFMA fp16 projection w/ hoisted wTg, R24 aggregate (16
// lanes/node, 4 nodes/wave, 4-deep, natural order), NT out stores, R29 slim
// mlp (37KB LDS), R17 CSR build, slice-write bn_stats (fence/atomic fusions
// proven losers on 8-XCD gfx950), scsh BN fusion into consumers.

__device__ __forceinline__ float leaky(float x) { return x > 0.f ? x : 0.2f * x; }

typedef float f32x4 __attribute__((ext_vector_type(4)));
typedef _Float16 f16x8 __attribute__((ext_vector_type(8)));

#define BCAP 4096  // max edges per 256-dst bucket (mean ~2560)
#define NSL 256    // bn_stats slices

// ---------------- CSR build ----------------
__global__ void bucket_hist(const int* __restrict__ dst, int* __restrict__ bcnt, int E) {
  __shared__ int cnt[512];
  int t = threadIdx.x;
  cnt[t] = 0; cnt[t + 256] = 0;
  __syncthreads();
  for (int e = blockIdx.x * blockDim.x + t; e < E; e += gridDim.x * blockDim.x)
    atomicAdd(&cnt[dst[e] >> 8], 1);
  __syncthreads();
  for (int i = t; i < 512; i += 256)
    if (cnt[i]) atomicAdd(&bcnt[i], cnt[i]);
}

__global__ void bucket_scan(const int* __restrict__ bcnt, int* __restrict__ boff,
                            int* __restrict__ bcur, int nbk) {
  __shared__ int temp[512];
  int t = threadIdx.x;  // 512 threads
  int v = (t < nbk) ? bcnt[t] : 0;
  temp[t] = v;
  __syncthreads();
  for (int off = 1; off < 512; off <<= 1) {
    int add = (t >= off) ? temp[t - off] : 0;
    __syncthreads();
    temp[t] += add;
    __syncthreads();
  }
  if (t < nbk) {
    int ex = temp[t] - v;
    boff[t] = ex;
    bcur[t] = ex;
  }
}

__global__ __launch_bounds__(256) void bin_scatter(
    const int* __restrict__ src, const int* __restrict__ dst,
    int* __restrict__ bcur, int2* __restrict__ ebuf, int E) {
  __shared__ int cnt[512];
  __shared__ int base[512];
  int t = threadIdx.x;
  int beg = blockIdx.x * 8192;
  int end = min(E, beg + 8192);
  cnt[t] = 0; cnt[t + 256] = 0;
  __syncthreads();
  for (int e = beg + t; e < end; e += 256)
    atomicAdd(&cnt[dst[e] >> 8], 1);
  __syncthreads();
  for (int i = t; i < 512; i += 256) {
    base[i] = cnt[i] ? atomicAdd(&bcur[i], cnt[i]) : 0;
    cnt[i] = 0;  // reuse as within-run cursor
  }
  __syncthreads();
  for (int e = beg + t; e < end; e += 256) {
    int d = dst[e];
    int bk = d >> 8;
    int off = atomicAdd(&cnt[bk], 1);
    ebuf[base[bk] + off] = make_int2(src[e], d);
  }
}

__global__ __launch_bounds__(256) void bucket_sort(
    const int2* __restrict__ ebuf, const int* __restrict__ boff,
    int* __restrict__ col, int* __restrict__ row_ptr, int E, int n, int nbk) {
  __shared__ int2 eds[BCAP];
  __shared__ int dcnt[256];
  __shared__ int dbase[256];
  __shared__ int dexcl[256];
  int b = blockIdx.x, t = threadIdx.x;
  int S = boff[b];
  int Eend = (b + 1 < nbk) ? boff[b + 1] : E;
  int cnt = min(Eend - S, BCAP);
  for (int i = t; i < cnt; i += 256) eds[i] = ebuf[S + i];
  dcnt[t] = 0;
  __syncthreads();
  for (int i = t; i < cnt; i += 256) atomicAdd(&dcnt[eds[i].y & 255], 1);
  __syncthreads();
  int v = dcnt[t];
  dbase[t] = v;
  __syncthreads();
  for (int off = 1; off < 256; off <<= 1) {
    int add = (t >= off) ? dbase[t - off] : 0;
    __syncthreads();
    dbase[t] += add;
    __syncthreads();
  }
  int excl = dbase[t] - v;
  int d = (b << 8) + t;
  if (d < n) row_ptr[d] = S + excl;
  if (b == nbk - 1 && t == 0) row_ptr[n] = E;
  dcnt[t] = 0;  // reuse as per-dst cursor
  dexcl[t] = excl;
  __syncthreads();
  for (int i = t; i < cnt; i += 256) {
    int2 e = eds[i];
    int dl = e.y & 255;
    int off = atomicAdd(&dcnt[dl], 1);
    col[S + dexcl[dl] + off] = e.x;
  }
}

// ---------------- W transpose + att-vector precombine (once) ----------------
// Per layer: wTg block [144][KE] fp16. Rows 0..127 = W^T columns; rows
// 128..131 = w_as0, w_as1, w_ad0, w_ad1 (w_as_h[k] = sum_c W[k][h*64+c] *
// att_s[h*64+c] — scores are linear in A); rows 132..143 zero.
// L0: KE=32 (K=16 zero-padded) @0; L1/L2: KE=64 @4608/@13824. 90x256 grid.
__global__ void transpose_ws(
    const float* __restrict__ W0, const float* __restrict__ W1,
    const float* __restrict__ W2,
    const float* __restrict__ as0, const float* __restrict__ ad0,
    const float* __restrict__ as1, const float* __restrict__ ad1,
    const float* __restrict__ as2, const float* __restrict__ ad2,
    __half* __restrict__ wTg) {
  int i = blockIdx.x * 256 + threadIdx.x;
  const float *W, *as, *ad;
  int KE, K, j;
  if (i < 4608)       { W = W0; as = as0; ad = ad0; KE = 32; K = 16; j = i; }
  else if (i < 13824) { W = W1; as = as1; ad = ad1; KE = 64; K = 64; j = i - 4608; }
  else if (i < 23040) { W = W2; as = as2; ad = ad2; KE = 64; K = 64; j = i - 13824; }
  else return;
  int r = j / KE, k = j % KE;
  float v = 0.f;
  if (k < K) {
    if (r < 128) {
      v = W[k * 128 + r];
    } else if (r < 132) {
      const float* att = (r & 2) ? ad : as;
      int h = r & 1;
      float acc = 0.f;
      for (int c = 0; c < 64; c++) acc += W[k * 128 + h * 64 + c] * att[h * 64 + c];
      v = acc;
    }
  }
  wTg[i] = __float2half(v);
}

// ---------------- BN stats (vectorized, slice writes) + finalize ----------
__global__ __launch_bounds__(256) void bn_stats(const float* __restrict__ h,
                                                float* __restrict__ stats, int n) {
  __shared__ float ssum[64], ssq[64];
  int t = threadIdx.x;
  if (t < 64) { ssum[t] = 0.f; ssq[t] = 0.f; }
  __syncthreads();
  const float4* h4 = (const float4*)h;
  size_t total4 = (size_t)n * 16;
  size_t stride = (size_t)gridDim.x * blockDim.x;   // multiple of 16
  int cbase = ((int)(((size_t)blockIdx.x * blockDim.x + t) & 15)) * 4;
  float s0 = 0.f, s1 = 0.f, s2 = 0.f, s3 = 0.f;
  float q0 = 0.f, q1 = 0.f, q2 = 0.f, q3 = 0.f;
  for (size_t i = (size_t)blockIdx.x * blockDim.x + t; i < total4; i += stride) {
    float4 v = h4[i];
    s0 += v.x; q0 = fmaf(v.x, v.x, q0);
    s1 += v.y; q1 = fmaf(v.y, v.y, q1);
    s2 += v.z; q2 = fmaf(v.z, v.z, q2);
    s3 += v.w; q3 = fmaf(v.w, v.w, q3);
  }
  atomicAdd(&ssum[cbase + 0], s0); atomicAdd(&ssq[cbase + 0], q0);
  atomicAdd(&ssum[cbase + 1], s1); atomicAdd(&ssq[cbase + 1], q1);
  atomicAdd(&ssum[cbase + 2], s2); atomicAdd(&ssq[cbase + 2], q2);
  atomicAdd(&ssum[cbase + 3], s3); atomicAdd(&ssq[cbase + 3], q3);
  __syncthreads();
  if (t < 64) {
    stats[blockIdx.x * 128 + t] = ssum[t];
    stats[blockIdx.x * 128 + 64 + t] = ssq[t];
  }
}

// reduce NSL slices -> scsh. 1024 threads: 8 groups x 128 channels (serial
// walk 256 -> 32 iters/thread; the 1-block 128-thread version was latency-
// bound at ~10us).
__global__ __launch_bounds__(1024) void bn_finalize(
    const float* __restrict__ stats, const float* __restrict__ g,
    const float* __restrict__ be, float* __restrict__ scsh, float inv_n) {
  __shared__ float red[1024];
  int t = threadIdx.x;
  int c = t & 127;   // 0..63 sum, 64..127 sumsq
  int grp = t >> 7;  // 0..7
  float acc = 0.f;
  for (int b = grp; b < NSL; b += 8) acc += stats[b * 128 + c];
  red[t] = acc;
  __syncthreads();
  if (t < 128) {
    float s = red[t];
#pragma unroll
    for (int j = 1; j < 8; j++) s += red[t + 128 * j];
    red[t] = s;  // each t<128 reads only column t -> in-place safe
  }
  __syncthreads();
  if (t < 64) {
    float mean = red[t] * inv_n;
    float var = red[64 + t] * inv_n - mean * mean;
    float sc = rsqrtf(var + 1e-5f) * g[t];
    scsh[t] = sc;
    scsh[64 + t] = be[t] - mean * sc;
  }
}

// ---------------- GAT projection: MFMA fp16, 64 nodes x (128+4) cols --------
// h = act @ W on the matrix pipe. 4 waves; wave w owns node rows w*16..+15,
// 9 col-tiles (tile 8 = score columns: as0,as1,ad0,ad1 from precombined
// att vectors — no shuffle epilogue). A[64][KP] staged fp16 (BN+ReLU fused);
// wT [144][KP] from pre-transposed wTg via coalesced uint4 copies. KP = KE+8
// (odd 16B stride -> conflict-free b128 fragment reads). C/D layout (m89):
// col=lane&15, row=(lane>>4)*4+reg.
template <int K, bool BN>
__global__ __launch_bounds__(256) void gat_project_mfma(
    const float* __restrict__ act, const float* __restrict__ scsh,
    const __half* __restrict__ wTg,
    __half2* __restrict__ hb, float* __restrict__ as_,
    float* __restrict__ ad_, int n) {
  constexpr int KE = (K < 32) ? 32 : K;   // effective (padded) K
  constexpr int KP = KE + 8;              // LDS stride in halves
  constexpr int STAGE = 64 * KP * 2 + 144 * KP * 2;
  constexpr int HSZ = 64 * 136 * 2;
  constexpr int LDSZ = (STAGE > HSZ) ? STAGE : HSZ;
  __shared__ __align__(16) char ldsb[LDSZ];
  __half* aH = (__half*)ldsb;                      // [64][KP]
  __half* wT = (__half*)(ldsb + 64 * KP * 2);      // [144][KP]
  __half* hS = (__half*)ldsb;                      // [64][136], aliases after barrier

  int t = threadIdx.x;
  int node0 = blockIdx.x * 64;
  int rows = min(64, n - node0);

  // ---- stage A: fp32 -> fp16, BN+ReLU fused; zero-pad r>=rows and k>=K
  constexpr int ACH = 64 * KE / 4;
  for (int i = t; i < ACH; i += 256) {
    int r = i / (KE / 4), kc = i % (KE / 4);
    float4 v = make_float4(0.f, 0.f, 0.f, 0.f);
    if (r < rows && kc * 4 < K)
      v = *(const float4*)&act[(size_t)(node0 + r) * K + kc * 4];
    if (BN) {
      float4 sc4 = *(const float4*)&scsh[kc * 4];
      float4 sh4 = *(const float4*)&scsh[64 + kc * 4];
      v.x = fmaxf(fmaf(v.x, sc4.x, sh4.x), 0.f);
      v.y = fmaxf(fmaf(v.y, sc4.y, sh4.y), 0.f);
      v.z = fmaxf(fmaf(v.z, sc4.z, sh4.z), 0.f);
      v.w = fmaxf(fmaf(v.w, sc4.w, sh4.w), 0.f);
    }
    __half2 h01 = __floats2half2_rn(v.x, v.y);
    __half2 h23 = __floats2half2_rn(v.z, v.w);
    uint2 pk = make_uint2(__builtin_bit_cast(unsigned, h01),
                          __builtin_bit_cast(unsigned, h23));
    *(uint2*)&aH[r * KP + kc * 4] = pk;
  }
  // ---- stage wT: coalesced uint4 copy from pre-transposed wTg [144][KE]
  constexpr int WCH = 144 * KE / 8;   // 16B chunks
  for (int i = t; i < WCH; i += 256) {
    int c = i / (KE / 8), j = i % (KE / 8);
    *(uint4*)&wT[c * KP + j * 8] = *(const uint4*)&wTg[c * KE + j * 8];
  }
  __syncthreads();

  int w = t >> 6, l = t & 63;
  int cl = l & 15, r4 = l >> 4;
  int w16 = w * 16;

  f32x4 acc[9] = {};
#pragma unroll
  for (int ks = 0; ks < KE / 32; ks++) {
    f16x8 av = *(const f16x8*)&aH[(w16 + cl) * KP + ks * 32 + r4 * 8];
#pragma unroll
    for (int ct = 0; ct < 9; ct++) {
      f16x8 bv = *(const f16x8*)&wT[(ct * 16 + cl) * KP + ks * 32 + r4 * 8];
      acc[ct] = __builtin_amdgcn_mfma_f32_16x16x32_f16(av, bv, acc[ct], 0, 0, 0);
    }
  }

  // ---- scores: direct lane writes from tile 8 (cols 128..131)
#pragma unroll
  for (int i = 0; i < 4; i++) {
    int rloc = w16 + r4 * 4 + i;
    if (rloc < rows && cl < 4) {
      int row = node0 + rloc;
      float sv = acc[8][i];
      if (cl == 0) as_[row * 2] = sv;
      else if (cl == 1) as_[row * 2 + 1] = sv;
      else if (cl == 2) ad_[row * 2] = sv;
      else ad_[row * 2 + 1] = sv;
    }
  }

  __syncthreads();  // aH/wT dead -> reuse as hS
  // ---- C fragments -> hS fp16 [64][136]
#pragma unroll
  for (int ct = 0; ct < 8; ct++)
#pragma unroll
    for (int i = 0; i < 4; i++)
      hS[(w16 + r4 * 4 + i) * 136 + ct * 16 + cl] = __float2half(acc[ct][i]);
  __syncthreads();
  // ---- hS -> hb, coalesced 16B chunks (256B per node row)
#pragma unroll
  for (int it = 0; it < 4; it++) {
    int flat = t + it * 256;
    int nd = flat >> 4, ch = flat & 15;
    if (nd < rows)
      *(uint4*)((char*)hb + (((size_t)(node0 + nd)) << 8) + (ch << 4)) =
          *(const uint4*)((const char*)hS + nd * 272 + (ch << 4));
  }
}

// ---------------- GAT aggregation: 16 lanes/node, 4 nodes/wave (R24) --------
// Natural node order (R28: degree-rank perm cost more locality than its
// balance bought). Lane q accumulates its 8 channels of head (q>=8) over ALL
// edges; 4-deep unroll = 4 independent 256B hb rows in flight per group;
// redundant per-lane den; 9-op head-swap epilogue; NT out stores.
__device__ __forceinline__ void fma8(float* a, float my, uint4 raw) {
  float2 f;
  f = __half22float2(__builtin_bit_cast(__half2, raw.x)); a[0] = fmaf(my, f.x, a[0]); a[1] = fmaf(my, f.y, a[1]);
  f = __half22float2(__builtin_bit_cast(__half2, raw.y)); a[2] = fmaf(my, f.x, a[2]); a[3] = fmaf(my, f.y, a[3]);
  f = __half22float2(__builtin_bit_cast(__half2, raw.z)); a[4] = fmaf(my, f.x, a[4]); a[5] = fmaf(my, f.y, a[5]);
  f = __half22float2(__builtin_bit_cast(__half2, raw.w)); a[6] = fmaf(my, f.x, a[6]); a[7] = fmaf(my, f.y, a[7]);
}

__global__ __launch_bounds__(256) void gat_aggregate(
    const __half2* __restrict__ hb,
    const float* __restrict__ as_, const float* __restrict__ ad_,
    const int* __restrict__ row_ptr, const int* __restrict__ col,
    const float* __restrict__ bias, float* __restrict__ out, int n) {
  int w = (int)((blockIdx.x * blockDim.x + threadIdx.x) >> 6);
  int lane = threadIdx.x & 63;
  int g = lane >> 4, q = lane & 15;
  int d = w * 4 + g;
  if (d >= n) return;  // diverges only in the last wave
  int hidx = (q >= 8) ? 1 : 0;
  int beg = row_ptr[d], end = row_ptr[d + 1];
  const uint4* hb4 = (const uint4*)hb;   // 16 uint4 per node (256 B)

  float ad_my = ad_[d * 2 + hidx];

  float a[8] = {};
  // self-loop (not in CSR)
  float asv = as_[d * 2 + hidx];
  float my = __expf(leaky(asv + ad_my));
  uint4 raw = hb4[(size_t)d * 16 + q];
  fma8(a, my, raw);
  float dpart = my;

  int k = beg;
  for (; k + 3 < end; k += 4) {
    int s0 = col[k], s1 = col[k + 1], s2 = col[k + 2], s3 = col[k + 3];
    float e0 = as_[s0 * 2 + hidx];
    float e1 = as_[s1 * 2 + hidx];
    float e2 = as_[s2 * 2 + hidx];
    float e3 = as_[s3 * 2 + hidx];
    uint4 r0 = hb4[(size_t)s0 * 16 + q];
    uint4 r1 = hb4[(size_t)s1 * 16 + q];
    uint4 r2 = hb4[(size_t)s2 * 16 + q];
    uint4 r3 = hb4[(size_t)s3 * 16 + q];
    float m0 = __expf(leaky(e0 + ad_my));
    float m1 = __expf(leaky(e1 + ad_my));
    float m2 = __expf(leaky(e2 + ad_my));
    float m3 = __expf(leaky(e3 + ad_my));
    fma8(a, m0, r0); fma8(a, m1, r1); fma8(a, m2, r2); fma8(a, m3, r3);
    dpart += m0 + m1 + m2 + m3;
  }
  for (; k < end; k++) {  // tail 0..3
    int s = col[k];
    float e = as_[s * 2 + hidx];
    uint4 r = hb4[(size_t)s * 16 + q];
    float m = __expf(leaky(e + ad_my));
    fma8(a, m, r);
    dpart += m;
  }

  // head swap within the 16-lane group (serves all 4 nodes of the wave)
  float b[8];
#pragma unroll
  for (int i = 0; i < 8; i++) b[i] = __shfl_xor(a[i], 8);
  float denO = __shfl_xor(dpart, 8);

  if (q < 8) {  // channels 8q..8q+7
    float rr0 = 1.f / (dpart + 1e-16f), rr1 = 1.f / (denO + 1e-16f);
    float4 bl = *(const float4*)&bias[q * 8];
    float4 bh = *(const float4*)&bias[q * 8 + 4];
    f32x4 o0, o1;
    o0.x = 0.5f * (a[0] * rr0 + b[0] * rr1) + bl.x;
    o0.y = 0.5f * (a[1] * rr0 + b[1] * rr1) + bl.y;
    o0.z = 0.5f * (a[2] * rr0 + b[2] * rr1) + bl.z;
    o0.w = 0.5f * (a[3] * rr0 + b[3] * rr1) + bl.w;
    o1.x = 0.5f * (a[4] * rr0 + b[4] * rr1) + bh.x;
    o1.y = 0.5f * (a[5] * rr0 + b[5] * rr1) + bh.y;
    o1.z = 0.5f * (a[6] * rr0 + b[6] * rr1) + bh.z;
    o1.w = 0.5f * (a[7] * rr0 + b[7] * rr1) + bh.w;
    f32x4* outp = (f32x4*)&out[(size_t)d * 64 + q * 8];
    __builtin_nontemporal_store(o0, outp);
    __builtin_nontemporal_store(o1, outp + 1);
  }
}

// ---------------- MLP head: fused tiled GEMM (64 nodes / block) --------------
// a1 staging applies BN(layer3 scsh)+ReLU to the raw aggregate output.
// LDS 37.1 KB: GEMM1 output written IN-PLACE over a1 (held in registers
// across a barrier), w2 staged over w1 -> 4 blocks/CU.
__global__ __launch_bounds__(256) void mlp_head_tiled(
    const float* __restrict__ h3raw, const float* __restrict__ scsh,
    const float* __restrict__ x,
    const float* __restrict__ mW1, const float* __restrict__ mb1,
    const float* __restrict__ mW2, const float* __restrict__ mb2,
    const float* __restrict__ pW, const float* __restrict__ pb,
    const float* __restrict__ vW, const float* __restrict__ vb,
    float* __restrict__ out, int n) {
  __shared__ float lds[9280];
  float* a1  = lds;           // 64*68 = 4352; GEMM1 input, then GEMM1 output
  float* ctx = lds + 4352;    // 64*8  = 512
  float* w1  = lds + 4864;    // 69*64 = 4416; then w2 (64*64 = 4096)

  int t = threadIdx.x;
  int node0 = blockIdx.x * 64;
  int rows = min(64, n - node0);

#pragma unroll
  for (int i = 0; i < 4; i++) {
    int flat = t + i * 256;
    int r = flat >> 4, kc = flat & 15;
    float4 v = make_float4(0.f, 0.f, 0.f, 0.f);
    if (r < rows) v = *(const float4*)&h3raw[(size_t)(node0 + r) * 64 + kc * 4];
    float4 sc4 = *(const float4*)&scsh[kc * 4];
    float4 sh4 = *(const float4*)&scsh[64 + kc * 4];
    v.x = fmaxf(fmaf(v.x, sc4.x, sh4.x), 0.f);
    v.y = fmaxf(fmaf(v.y, sc4.y, sh4.y), 0.f);
    v.z = fmaxf(fmaf(v.z, sc4.z, sh4.z), 0.f);
    v.w = fmaxf(fmaf(v.w, sc4.w, sh4.w), 0.f);
    *(float4*)&a1[r * 68 + kc * 4] = v;
  }
  for (int i = t; i < 320; i += 256) {
    int r = i / 5, j = i % 5;
    ctx[r * 8 + j] = (r < rows) ? x[(size_t)(node0 + r) * 16 + 9 + j] : 0.f;
  }
#pragma unroll
  for (int i = 0; i < 5; i++) {
    int flat = t + i * 256;
    if (flat < 1104) *(float4*)&w1[flat * 4] = *(const float4*)&mW1[flat * 4];
  }
  __syncthreads();

  int tc = t & 15, tr = t >> 4;
  int c0 = tc * 4, r0 = tr * 4;

  float acc[4][4] = {};
  for (int k = 0; k < 64; k += 4) {
    float4 av[4], wv[4];
#pragma unroll
    for (int i = 0; i < 4; i++) av[i] = *(const float4*)&a1[(r0 + i) * 68 + k];
#pragma unroll
    for (int j = 0; j < 4; j++) wv[j] = *(const float4*)&w1[(k + j) * 64 + c0];
#pragma unroll
    for (int i = 0; i < 4; i++) {
      const float* ai = (const float*)&av[i];
#pragma unroll
      for (int kk = 0; kk < 4; kk++) {
        const float* wr = (const float*)&wv[kk];
        acc[i][0] = fmaf(ai[kk], wr[0], acc[i][0]);
        acc[i][1] = fmaf(ai[kk], wr[1], acc[i][1]);
        acc[i][2] = fmaf(ai[kk], wr[2], acc[i][2]);
        acc[i][3] = fmaf(ai[kk], wr[3], acc[i][3]);
      }
    }
  }
#pragma unroll
  for (int k = 64; k < 69; k++) {
    float4 wv = *(const float4*)&w1[k * 64 + c0];
    const float* wr = (const float*)&wv;
#pragma unroll
    for (int i = 0; i < 4; i++) {
      float a = ctx[(r0 + i) * 8 + (k - 64)];
      acc[i][0] = fmaf(a, wr[0], acc[i][0]);
      acc[i][1] = fmaf(a, wr[1], acc[i][1]);
      acc[i][2] = fmaf(a, wr[2], acc[i][2]);
      acc[i][3] = fmaf(a, wr[3], acc[i][3]);
    }
  }
  float b1v0 = mb1[c0], b1v1 = mb1[c0 + 1], b1v2 = mb1[c0 + 2], b1v3 = mb1[c0 + 3];
  float4 t1v[4];
#pragma unroll
  for (int i = 0; i < 4; i++) {
    t1v[i].x = fmaxf(acc[i][0] + b1v0, 0.f);
    t1v[i].y = fmaxf(acc[i][1] + b1v1, 0.f);
    t1v[i].z = fmaxf(acc[i][2] + b1v2, 0.f);
    t1v[i].w = fmaxf(acc[i][3] + b1v3, 0.f);
  }
  __syncthreads();  // all GEMM1 reads of a1/w1 done -> regions reusable

  // GEMM1 output in-place over a1; w2 over w1
#pragma unroll
  for (int i = 0; i < 4; i++)
    *(float4*)&a1[(r0 + i) * 68 + c0] = t1v[i];
#pragma unroll
  for (int i = 0; i < 4; i++) {
    int flat = t + i * 256;
    *(float4*)&w1[flat * 4] = *(const float4*)&mW2[flat * 4];
  }
  __syncthreads();

  float acc2[4][4] = {};
  for (int k = 0; k < 64; k += 4) {
    float4 av[4], wv[4];
#pragma unroll
    for (int i = 0; i < 4; i++) av[i] = *(const float4*)&a1[(r0 + i) * 68 + k];
#pragma unroll
    for (int j = 0; j < 4; j++) wv[j] = *(const float4*)&w1[(k + j) * 64 + c0];
#pragma unroll
    for (int i = 0; i < 4; i++) {
      const float* ai = (const float*)&av[i];
#pragma unroll
      for (int kk = 0; kk < 4; kk++) {
        const float* wr = (const float*)&wv[kk];
        acc2[i][0] = fmaf(ai[kk], wr[0], acc2[i][0]);
        acc2[i][1] = fmaf(ai[kk], wr[1], acc2[i][1]);
        acc2[i][2] = fmaf(ai[kk], wr[2], acc2[i][2]);
        acc2[i][3] = fmaf(ai[kk], wr[3], acc2[i][3]);
      }
    }
  }

  float b2v[4], pwv[4], vwv[4];
#pragma unroll
  for (int j = 0; j < 4; j++) {
    b2v[j] = mb2[c0 + j];
    pwv[j] = pW[c0 + j];
    vwv[j] = vW[c0 + j];
  }
  float p[4], v[4];
#pragma unroll
  for (int i = 0; i < 4; i++) {
    float ps = 0.f, vs = 0.f;
#pragma unroll
    for (int j = 0; j < 4; j++) {
      float u = acc2[i][j] + b2v[j];
      ps = fmaf(u, pwv[j], ps);
      vs = fmaf(u, vwv[j], vs);
    }
    p[i] = ps; v[i] = vs;
  }
#pragma unroll
  for (int off = 1; off < 16; off <<= 1) {
#pragma unroll
    for (int i = 0; i < 4; i++) {
      p[i] += __shfl_xor(p[i], off);
      v[i] += __shfl_xor(v[i], off);
    }
  }
  if (tc == 0) {
    float pbs = pb[0], vbs = vb[0];
#pragma unroll
    for (int i = 0; i < 4; i++) {
      int r = r0 + i;
      if (r < rows) {
        out[node0 + r] = p[i] + pbs;
        out[n + node0 + r] = v[i] + vbs;
      }
    }
  }
}

extern "C" void kernel_launch(void* const* d_in, const int* in_sizes, int n_in,
                              void* d_out, int out_size, void* d_ws, size_t ws_size,
                              hipStream_t stream) {
  const float* x = (const float*)d_in[0];
  const int* ei = (const int*)d_in[1];
  const float* W[3]  = {(const float*)d_in[2],  (const float*)d_in[8],  (const float*)d_in[14]};
  const float* AS[3] = {(const float*)d_in[3],  (const float*)d_in[9],  (const float*)d_in[15]};
  const float* AD[3] = {(const float*)d_in[4],  (const float*)d_in[10], (const float*)d_in[16]};
  const float* B[3]  = {(const float*)d_in[5],  (const float*)d_in[11], (const float*)d_in[17]};
  const float* G[3]  = {(const float*)d_in[6],  (const float*)d_in[12], (const float*)d_in[18]};
  const float* BE[3] = {(const float*)d_in[7],  (const float*)d_in[13], (const float*)d_in[19]};
  const float* mW1 = (const float*)d_in[20];
  const float* mb1 = (const float*)d_in[21];
  const float* mW2 = (const float*)d_in[22];
  const float* mb2 = (const float*)d_in[23];
  const float* pW  = (const float*)d_in[24];
  const float* pb  = (const float*)d_in[25];
  const float* vW  = (const float*)d_in[26];
  const float* vb  = (const float*)d_in[27];

  const int N = in_sizes[0] / 16;
  const int E = in_sizes[1] / 2;
  const int* srcp = ei;
  const int* dstp = ei + E;

  // workspace carve-up (~65 MB)
  float* bufB  = (float*)d_ws;               // N*64  raw aggregate output
  float* hbuf  = bufB + (size_t)N * 64;      // N*64 half2 region (N*64 f32 bytes)
  float* as_   = hbuf + (size_t)N * 64;      // N*2
  float* ad_   = as_ + (size_t)N * 2;        // N*2
  float* stats = ad_ + (size_t)N * 2;        // NSL*128
  float* scsh  = stats + NSL * 128;          // 128
  __half* wTg  = (__half*)(scsh + 128);      // 23040 halves (3 x [144][KE])
  int* row_ptr = (int*)(wTg + 23040);        // N+1
  int* bcnt    = row_ptr + (N + 1);          // 512
  int* boff    = bcnt + 512;                 // 512
  int* bcur    = boff + 512;                 // 512
  int* col     = bcur + 512;                 // E ints (sorted CSR, src only)
  int2* ebuf   = (int2*)(col + E);           // E int2 (staging)
  __half2* hb  = (__half2*)hbuf;
  const __half* wTgL[3] = {wTg, wTg + 4608, wTg + 13824};

  const int nbk = (N + 255) >> 8;
  const float inv_n = 1.0f / (float)N;

  // ---- W transposes + att precombine (once) + CSR build
  transpose_ws<<<90, 256, 0, stream>>>(W[0], W[1], W[2], AS[0], AD[0],
                                       AS[1], AD[1], AS[2], AD[2], wTg);
  hipMemsetAsync(bcnt, 0, sizeof(int) * 512, stream);
  bucket_hist<<<256, 256, 0, stream>>>(dstp, bcnt, E);
  bucket_scan<<<1, 512, 0, stream>>>(bcnt, boff, bcur, nbk);
  bin_scatter<<<(E + 8191) / 8192, 256, 0, stream>>>(srcp, dstp, bcur, ebuf, E);
  bucket_sort<<<nbk, 256, 0, stream>>>(ebuf, boff, col, row_ptr, E, N, nbk);

  const int tiles = (N + 63) / 64;
  const int agg_blocks = (N + 15) / 16;  // 4 nodes/wave, 4 waves/block

  // ---- 3 GAT layers (BN+ReLU fused into the next consumer via scsh)
  for (int l = 0; l < 3; l++) {
    if (l == 0)
      gat_project_mfma<16, false><<<tiles, 256, 0, stream>>>(x, scsh, wTgL[l],
                                                             hb, as_, ad_, N);
    else
      gat_project_mfma<64, true><<<tiles, 256, 0, stream>>>(bufB, scsh, wTgL[l],
                                                            hb, as_, ad_, N);
    gat_aggregate<<<agg_blocks, 256, 0, stream>>>(hb, as_, ad_, row_ptr, col,
                                                  B[l], bufB, N);
    bn_stats<<<NSL, 256, 0, stream>>>(bufB, stats, N);
    bn_finalize<<<1, 1024, 0, stream>>>(stats, G[l], BE[l], scsh, inv_n);
  }

  // ---- MLP head -> (logits, value); applies layer-3 BN+ReLU to bufB
  mlp_head_tiled<<<tiles, 256, 0, stream>>>(bufB, scsh, x, mW1, mb1, mW2, mb2,
                                            pW, pb, vW, vb, (float*)d_out, N);
}

// Round 14
// 441.624 us; speedup vs baseline: 1.4008x; 1.0251x over previous
//
#include <hip/hip_runtime.h>
#include <hip/hip_fp16.h>

// N=100000 nodes, E=1000000 edges, D_IN=16, H=2, C=64.
// 3x (GAT -> BN -> ReLU), then MLP head -> (logits, value) concat in d_out.
// R32 = R31 (452.7us best) + bufB (layer activations) stored fp16.
// Every consumer of bufB rounds to fp16 anyway (projection converts for
// MFMA; hb is fp16) — fp32 carriage doubled 4 HBM streams: aggregate WRITE,
// bn_stats FETCH, projection A-stage FETCH (x2 layers), mlp FETCH. Only new
// rounding is where rounding already happened; BN stats now computed from
// the same fp16-rounded values consumers see (self-consistent).
// Kept: R31 MFMA-score projection (scores on matrix pipe via precombined
// att vectors), hoisted wTg transpose, R24 aggregate (16 lanes/node, 4
// nodes/wave, 4-deep, natural order), NT out stores, R29 slim mlp, R17 CSR
// build, slice-write bn_stats + 1024-thread bn_finalize, scsh BN fusion.

__device__ __forceinline__ float leaky(float x) { return x > 0.f ? x : 0.2f * x; }

typedef float f32x4 __attribute__((ext_vector_type(4)));
typedef _Float16 f16x8 __attribute__((ext_vector_type(8)));
typedef unsigned int u32x4 __attribute__((ext_vector_type(4)));

#define BCAP 4096  // max edges per 256-dst bucket (mean ~2560)
#define NSL 256    // bn_stats slices

// ---------------- CSR build ----------------
__global__ void bucket_hist(const int* __restrict__ dst, int* __restrict__ bcnt, int E) {
  __shared__ int cnt[512];
  int t = threadIdx.x;
  cnt[t] = 0; cnt[t + 256] = 0;
  __syncthreads();
  for (int e = blockIdx.x * blockDim.x + t; e < E; e += gridDim.x * blockDim.x)
    atomicAdd(&cnt[dst[e] >> 8], 1);
  __syncthreads();
  for (int i = t; i < 512; i += 256)
    if (cnt[i]) atomicAdd(&bcnt[i], cnt[i]);
}

__global__ void bucket_scan(const int* __restrict__ bcnt, int* __restrict__ boff,
                            int* __restrict__ bcur, int nbk) {
  __shared__ int temp[512];
  int t = threadIdx.x;  // 512 threads
  int v = (t < nbk) ? bcnt[t] : 0;
  temp[t] = v;
  __syncthreads();
  for (int off = 1; off < 512; off <<= 1) {
    int add = (t >= off) ? temp[t - off] : 0;
    __syncthreads();
    temp[t] += add;
    __syncthreads();
  }
  if (t < nbk) {
    int ex = temp[t] - v;
    boff[t] = ex;
    bcur[t] = ex;
  }
}

__global__ __launch_bounds__(256) void bin_scatter(
    const int* __restrict__ src, const int* __restrict__ dst,
    int* __restrict__ bcur, int2* __restrict__ ebuf, int E) {
  __shared__ int cnt[512];
  __shared__ int base[512];
  int t = threadIdx.x;
  int beg = blockIdx.x * 8192;
  int end = min(E, beg + 8192);
  cnt[t] = 0; cnt[t + 256] = 0;
  __syncthreads();
  for (int e = beg + t; e < end; e += 256)
    atomicAdd(&cnt[dst[e] >> 8], 1);
  __syncthreads();
  for (int i = t; i < 512; i += 256) {
    base[i] = cnt[i] ? atomicAdd(&bcur[i], cnt[i]) : 0;
    cnt[i] = 0;  // reuse as within-run cursor
  }
  __syncthreads();
  for (int e = beg + t; e < end; e += 256) {
    int d = dst[e];
    int bk = d >> 8;
    int off = atomicAdd(&cnt[bk], 1);
    ebuf[base[bk] + off] = make_int2(src[e], d);
  }
}

__global__ __launch_bounds__(256) void bucket_sort(
    const int2* __restrict__ ebuf, const int* __restrict__ boff,
    int* __restrict__ col, int* __restrict__ row_ptr, int E, int n, int nbk) {
  __shared__ int2 eds[BCAP];
  __shared__ int dcnt[256];
  __shared__ int dbase[256];
  __shared__ int dexcl[256];
  int b = blockIdx.x, t = threadIdx.x;
  int S = boff[b];
  int Eend = (b + 1 < nbk) ? boff[b + 1] : E;
  int cnt = min(Eend - S, BCAP);
  for (int i = t; i < cnt; i += 256) eds[i] = ebuf[S + i];
  dcnt[t] = 0;
  __syncthreads();
  for (int i = t; i < cnt; i += 256) atomicAdd(&dcnt[eds[i].y & 255], 1);
  __syncthreads();
  int v = dcnt[t];
  dbase[t] = v;
  __syncthreads();
  for (int off = 1; off < 256; off <<= 1) {
    int add = (t >= off) ? dbase[t - off] : 0;
    __syncthreads();
    dbase[t] += add;
    __syncthreads();
  }
  int excl = dbase[t] - v;
  int d = (b << 8) + t;
  if (d < n) row_ptr[d] = S + excl;
  if (b == nbk - 1 && t == 0) row_ptr[n] = E;
  dcnt[t] = 0;  // reuse as per-dst cursor
  dexcl[t] = excl;
  __syncthreads();
  for (int i = t; i < cnt; i += 256) {
    int2 e = eds[i];
    int dl = e.y & 255;
    int off = atomicAdd(&dcnt[dl], 1);
    col[S + dexcl[dl] + off] = e.x;
  }
}

// ---------------- W transpose + att-vector precombine (once) ----------------
// Per layer: wTg block [144][KE] fp16. Rows 0..127 = W^T columns; rows
// 128..131 = w_as0, w_as1, w_ad0, w_ad1 (scores are linear in A); rows
// 132..143 zero. L0: KE=32 @0; L1/L2: KE=64 @4608/@13824. 90x256 grid.
__global__ void transpose_ws(
    const float* __restrict__ W0, const float* __restrict__ W1,
    const float* __restrict__ W2,
    const float* __restrict__ as0, const float* __restrict__ ad0,
    const float* __restrict__ as1, const float* __restrict__ ad1,
    const float* __restrict__ as2, const float* __restrict__ ad2,
    __half* __restrict__ wTg) {
  int i = blockIdx.x * 256 + threadIdx.x;
  const float *W, *as, *ad;
  int KE, K, j;
  if (i < 4608)       { W = W0; as = as0; ad = ad0; KE = 32; K = 16; j = i; }
  else if (i < 13824) { W = W1; as = as1; ad = ad1; KE = 64; K = 64; j = i - 4608; }
  else if (i < 23040) { W = W2; as = as2; ad = ad2; KE = 64; K = 64; j = i - 13824; }
  else return;
  int r = j / KE, k = j % KE;
  float v = 0.f;
  if (k < K) {
    if (r < 128) {
      v = W[k * 128 + r];
    } else if (r < 132) {
      const float* att = (r & 2) ? ad : as;
      int h = r & 1;
      float acc = 0.f;
      for (int c = 0; c < 64; c++) acc += W[k * 128 + h * 64 + c] * att[h * 64 + c];
      v = acc;
    }
  }
  wTg[i] = __float2half(v);
}

// ---------------- BN stats (fp16 input, slice writes) + finalize ----------
__global__ __launch_bounds__(256) void bn_stats(const __half* __restrict__ h,
                                                float* __restrict__ stats, int n) {
  __shared__ float ssum[64], ssq[64];
  int t = threadIdx.x;
  if (t < 64) { ssum[t] = 0.f; ssq[t] = 0.f; }
  __syncthreads();
  const uint4* h4 = (const uint4*)h;      // 8 halves per chunk
  size_t total = (size_t)n * 8;
  size_t stride = (size_t)gridDim.x * blockDim.x;   // multiple of 8
  int cbase = (t & 7) * 8;
  float s[8] = {}, qq[8] = {};
  for (size_t i = (size_t)blockIdx.x * blockDim.x + t; i < total; i += stride) {
    uint4 v = h4[i];
    float2 f0 = __half22float2(__builtin_bit_cast(__half2, v.x));
    float2 f1 = __half22float2(__builtin_bit_cast(__half2, v.y));
    float2 f2 = __half22float2(__builtin_bit_cast(__half2, v.z));
    float2 f3 = __half22float2(__builtin_bit_cast(__half2, v.w));
    s[0] += f0.x; qq[0] = fmaf(f0.x, f0.x, qq[0]);
    s[1] += f0.y; qq[1] = fmaf(f0.y, f0.y, qq[1]);
    s[2] += f1.x; qq[2] = fmaf(f1.x, f1.x, qq[2]);
    s[3] += f1.y; qq[3] = fmaf(f1.y, f1.y, qq[3]);
    s[4] += f2.x; qq[4] = fmaf(f2.x, f2.x, qq[4]);
    s[5] += f2.y; qq[5] = fmaf(f2.y, f2.y, qq[5]);
    s[6] += f3.x; qq[6] = fmaf(f3.x, f3.x, qq[6]);
    s[7] += f3.y; qq[7] = fmaf(f3.y, f3.y, qq[7]);
  }
#pragma unroll
  for (int j = 0; j < 8; j++) {
    atomicAdd(&ssum[cbase + j], s[j]);
    atomicAdd(&ssq[cbase + j], qq[j]);
  }
  __syncthreads();
  if (t < 64) {
    stats[blockIdx.x * 128 + t] = ssum[t];
    stats[blockIdx.x * 128 + 64 + t] = ssq[t];
  }
}

// reduce NSL slices -> scsh. 1024 threads: 8 groups x 128 channels.
__global__ __launch_bounds__(1024) void bn_finalize(
    const float* __restrict__ stats, const float* __restrict__ g,
    const float* __restrict__ be, float* __restrict__ scsh, float inv_n) {
  __shared__ float red[1024];
  int t = threadIdx.x;
  int c = t & 127;   // 0..63 sum, 64..127 sumsq
  int grp = t >> 7;  // 0..7
  float acc = 0.f;
  for (int b = grp; b < NSL; b += 8) acc += stats[b * 128 + c];
  red[t] = acc;
  __syncthreads();
  if (t < 128) {
    float s = red[t];
#pragma unroll
    for (int j = 1; j < 8; j++) s += red[t + 128 * j];
    red[t] = s;  // each t<128 reads only column t -> in-place safe
  }
  __syncthreads();
  if (t < 64) {
    float mean = red[t] * inv_n;
    float var = red[64 + t] * inv_n - mean * mean;
    float sc = rsqrtf(var + 1e-5f) * g[t];
    scsh[t] = sc;
    scsh[64 + t] = be[t] - mean * sc;
  }
}

// ---------------- GAT projection: MFMA fp16, 64 nodes x (128+4) cols --------
// h = act @ W on the matrix pipe. 4 waves; 9 col-tiles (tile 8 = score
// columns from precombined att vectors). BN=true: act is fp16 bufB (16B
// chunk staging); BN=false: act is fp32 x. wT [144][KP] from wTg via
// coalesced uint4. KP = KE+8 (conflict-free b128 frag reads). C/D layout
// (m89): col=lane&15, row=(lane>>4)*4+reg.
template <int K, bool BN>
__global__ __launch_bounds__(256) void gat_project_mfma(
    const void* __restrict__ act, const float* __restrict__ scsh,
    const __half* __restrict__ wTg,
    __half2* __restrict__ hb, float* __restrict__ as_,
    float* __restrict__ ad_, int n) {
  constexpr int KE = (K < 32) ? 32 : K;   // effective (padded) K
  constexpr int KP = KE + 8;              // LDS stride in halves
  constexpr int STAGE = 64 * KP * 2 + 144 * KP * 2;
  constexpr int HSZ = 64 * 136 * 2;
  constexpr int LDSZ = (STAGE > HSZ) ? STAGE : HSZ;
  __shared__ __align__(16) char ldsb[LDSZ];
  __half* aH = (__half*)ldsb;                      // [64][KP]
  __half* wT = (__half*)(ldsb + 64 * KP * 2);      // [144][KP]
  __half* hS = (__half*)ldsb;                      // [64][136], aliases after barrier

  int t = threadIdx.x;
  int node0 = blockIdx.x * 64;
  int rows = min(64, n - node0);

  if constexpr (BN) {
    // act = fp16 [n][64]; BN+ReLU in fp32, restore fp16; 16B chunks
    const __half* a16 = (const __half*)act;
    for (int i = t; i < 512; i += 256) {     // 64 rows x 8 chunks
      int r = i >> 3, kc = i & 7;
      uint4 hv = make_uint4(0, 0, 0, 0);
      if (r < rows) hv = *(const uint4*)(a16 + (size_t)(node0 + r) * 64 + kc * 8);
      float2 f0 = __half22float2(__builtin_bit_cast(__half2, hv.x));
      float2 f1 = __half22float2(__builtin_bit_cast(__half2, hv.y));
      float2 f2 = __half22float2(__builtin_bit_cast(__half2, hv.z));
      float2 f3 = __half22float2(__builtin_bit_cast(__half2, hv.w));
      const float* sc = &scsh[kc * 8];
      const float* sh = &scsh[64 + kc * 8];
      f0.x = fmaxf(fmaf(f0.x, sc[0], sh[0]), 0.f);
      f0.y = fmaxf(fmaf(f0.y, sc[1], sh[1]), 0.f);
      f1.x = fmaxf(fmaf(f1.x, sc[2], sh[2]), 0.f);
      f1.y = fmaxf(fmaf(f1.y, sc[3], sh[3]), 0.f);
      f2.x = fmaxf(fmaf(f2.x, sc[4], sh[4]), 0.f);
      f2.y = fmaxf(fmaf(f2.y, sc[5], sh[5]), 0.f);
      f3.x = fmaxf(fmaf(f3.x, sc[6], sh[6]), 0.f);
      f3.y = fmaxf(fmaf(f3.y, sc[7], sh[7]), 0.f);
      uint4 pk;
      pk.x = __builtin_bit_cast(unsigned, __floats2half2_rn(f0.x, f0.y));
      pk.y = __builtin_bit_cast(unsigned, __floats2half2_rn(f1.x, f1.y));
      pk.z = __builtin_bit_cast(unsigned, __floats2half2_rn(f2.x, f2.y));
      pk.w = __builtin_bit_cast(unsigned, __floats2half2_rn(f3.x, f3.y));
      *(uint4*)&aH[r * KP + kc * 8] = pk;
    }
  } else {
    // act = fp32 x [n][K]; zero-pad k>=K
    const float* a32 = (const float*)act;
    constexpr int ACH = 64 * KE / 4;
    for (int i = t; i < ACH; i += 256) {
      int r = i / (KE / 4), kc = i % (KE / 4);
      float4 v = make_float4(0.f, 0.f, 0.f, 0.f);
      if (r < rows && kc * 4 < K)
        v = *(const float4*)&a32[(size_t)(node0 + r) * K + kc * 4];
      __half2 h01 = __floats2half2_rn(v.x, v.y);
      __half2 h23 = __floats2half2_rn(v.z, v.w);
      uint2 pk = make_uint2(__builtin_bit_cast(unsigned, h01),
                            __builtin_bit_cast(unsigned, h23));
      *(uint2*)&aH[r * KP + kc * 4] = pk;
    }
  }
  // ---- stage wT: coalesced uint4 copy from pre-transposed wTg [144][KE]
  constexpr int WCH = 144 * KE / 8;   // 16B chunks
  for (int i = t; i < WCH; i += 256) {
    int c = i / (KE / 8), j = i % (KE / 8);
    *(uint4*)&wT[c * KP + j * 8] = *(const uint4*)&wTg[c * KE + j * 8];
  }
  __syncthreads();

  int w = t >> 6, l = t & 63;
  int cl = l & 15, r4 = l >> 4;
  int w16 = w * 16;

  f32x4 acc[9] = {};
#pragma unroll
  for (int ks = 0; ks < KE / 32; ks++) {
    f16x8 av = *(const f16x8*)&aH[(w16 + cl) * KP + ks * 32 + r4 * 8];
#pragma unroll
    for (int ct = 0; ct < 9; ct++) {
      f16x8 bv = *(const f16x8*)&wT[(ct * 16 + cl) * KP + ks * 32 + r4 * 8];
      acc[ct] = __builtin_amdgcn_mfma_f32_16x16x32_f16(av, bv, acc[ct], 0, 0, 0);
    }
  }

  // ---- scores: direct lane writes from tile 8 (cols 128..131)
#pragma unroll
  for (int i = 0; i < 4; i++) {
    int rloc = w16 + r4 * 4 + i;
    if (rloc < rows && cl < 4) {
      int row = node0 + rloc;
      float sv = acc[8][i];
      if (cl == 0) as_[row * 2] = sv;
      else if (cl == 1) as_[row * 2 + 1] = sv;
      else if (cl == 2) ad_[row * 2] = sv;
      else ad_[row * 2 + 1] = sv;
    }
  }

  __syncthreads();  // aH/wT dead -> reuse as hS
  // ---- C fragments -> hS fp16 [64][136]
#pragma unroll
  for (int ct = 0; ct < 8; ct++)
#pragma unroll
    for (int i = 0; i < 4; i++)
      hS[(w16 + r4 * 4 + i) * 136 + ct * 16 + cl] = __float2half(acc[ct][i]);
  __syncthreads();
  // ---- hS -> hb, coalesced 16B chunks (256B per node row)
#pragma unroll
  for (int it = 0; it < 4; it++) {
    int flat = t + it * 256;
    int nd = flat >> 4, ch = flat & 15;
    if (nd < rows)
      *(uint4*)((char*)hb + (((size_t)(node0 + nd)) << 8) + (ch << 4)) =
          *(const uint4*)((const char*)hS + nd * 272 + (ch << 4));
  }
}

// ---------------- GAT aggregation: 16 lanes/node, 4 nodes/wave (R24) --------
// Natural node order. Lane q accumulates its 8 channels of head (q>=8) over
// ALL edges; 4-deep unroll; redundant per-lane den; 9-op head-swap epilogue.
// Output bufB is fp16 (128B/node row), one 16B NT store per lane q<8.
__device__ __forceinline__ void fma8(float* a, float my, uint4 raw) {
  float2 f;
  f = __half22float2(__builtin_bit_cast(__half2, raw.x)); a[0] = fmaf(my, f.x, a[0]); a[1] = fmaf(my, f.y, a[1]);
  f = __half22float2(__builtin_bit_cast(__half2, raw.y)); a[2] = fmaf(my, f.x, a[2]); a[3] = fmaf(my, f.y, a[3]);
  f = __half22float2(__builtin_bit_cast(__half2, raw.z)); a[4] = fmaf(my, f.x, a[4]); a[5] = fmaf(my, f.y, a[5]);
  f = __half22float2(__builtin_bit_cast(__half2, raw.w)); a[6] = fmaf(my, f.x, a[6]); a[7] = fmaf(my, f.y, a[7]);
}

__global__ __launch_bounds__(256) void gat_aggregate(
    const __half2* __restrict__ hb,
    const float* __restrict__ as_, const float* __restrict__ ad_,
    const int* __restrict__ row_ptr, const int* __restrict__ col,
    const float* __restrict__ bias, __half* __restrict__ out, int n) {
  int w = (int)((blockIdx.x * blockDim.x + threadIdx.x) >> 6);
  int lane = threadIdx.x & 63;
  int g = lane >> 4, q = lane & 15;
  int d = w * 4 + g;
  if (d >= n) return;  // diverges only in the last wave
  int hidx = (q >= 8) ? 1 : 0;
  int beg = row_ptr[d], end = row_ptr[d + 1];
  const uint4* hb4 = (const uint4*)hb;   // 16 uint4 per node (256 B)

  float ad_my = ad_[d * 2 + hidx];

  float a[8] = {};
  // self-loop (not in CSR)
  float asv = as_[d * 2 + hidx];
  float my = __expf(leaky(asv + ad_my));
  uint4 raw = hb4[(size_t)d * 16 + q];
  fma8(a, my, raw);
  float dpart = my;

  int k = beg;
  for (; k + 3 < end; k += 4) {
    int s0 = col[k], s1 = col[k + 1], s2 = col[k + 2], s3 = col[k + 3];
    float e0 = as_[s0 * 2 + hidx];
    float e1 = as_[s1 * 2 + hidx];
    float e2 = as_[s2 * 2 + hidx];
    float e3 = as_[s3 * 2 + hidx];
    uint4 r0 = hb4[(size_t)s0 * 16 + q];
    uint4 r1 = hb4[(size_t)s1 * 16 + q];
    uint4 r2 = hb4[(size_t)s2 * 16 + q];
    uint4 r3 = hb4[(size_t)s3 * 16 + q];
    float m0 = __expf(leaky(e0 + ad_my));
    float m1 = __expf(leaky(e1 + ad_my));
    float m2 = __expf(leaky(e2 + ad_my));
    float m3 = __expf(leaky(e3 + ad_my));
    fma8(a, m0, r0); fma8(a, m1, r1); fma8(a, m2, r2); fma8(a, m3, r3);
    dpart += m0 + m1 + m2 + m3;
  }
  for (; k < end; k++) {  // tail 0..3
    int s = col[k];
    float e = as_[s * 2 + hidx];
    uint4 r = hb4[(size_t)s * 16 + q];
    float m = __expf(leaky(e + ad_my));
    fma8(a, m, r);
    dpart += m;
  }

  // head swap within the 16-lane group (serves all 4 nodes of the wave)
  float b[8];
#pragma unroll
  for (int i = 0; i < 8; i++) b[i] = __shfl_xor(a[i], 8);
  float denO = __shfl_xor(dpart, 8);

  if (q < 8) {  // channels 8q..8q+7
    float rr0 = 1.f / (dpart + 1e-16f), rr1 = 1.f / (denO + 1e-16f);
    float4 bl = *(const float4*)&bias[q * 8];
    float4 bh = *(const float4*)&bias[q * 8 + 4];
    float o[8];
    o[0] = 0.5f * (a[0] * rr0 + b[0] * rr1) + bl.x;
    o[1] = 0.5f * (a[1] * rr0 + b[1] * rr1) + bl.y;
    o[2] = 0.5f * (a[2] * rr0 + b[2] * rr1) + bl.z;
    o[3] = 0.5f * (a[3] * rr0 + b[3] * rr1) + bl.w;
    o[4] = 0.5f * (a[4] * rr0 + b[4] * rr1) + bh.x;
    o[5] = 0.5f * (a[5] * rr0 + b[5] * rr1) + bh.y;
    o[6] = 0.5f * (a[6] * rr0 + b[6] * rr1) + bh.z;
    o[7] = 0.5f * (a[7] * rr0 + b[7] * rr1) + bh.w;
    u32x4 pk;
    pk.x = __builtin_bit_cast(unsigned, __floats2half2_rn(o[0], o[1]));
    pk.y = __builtin_bit_cast(unsigned, __floats2half2_rn(o[2], o[3]));
    pk.z = __builtin_bit_cast(unsigned, __floats2half2_rn(o[4], o[5]));
    pk.w = __builtin_bit_cast(unsigned, __floats2half2_rn(o[6], o[7]));
    u32x4* outp = (u32x4*)((char*)out + (((size_t)d) << 7) + (q << 4));
    __builtin_nontemporal_store(pk, outp);
  }
}

// ---------------- MLP head: fused tiled GEMM (64 nodes / block) --------------
// a1 staging applies BN(layer3 scsh)+ReLU to the fp16 aggregate output.
// LDS 37.1 KB: GEMM1 output written IN-PLACE over a1, w2 over w1.
__global__ __launch_bounds__(256) void mlp_head_tiled(
    const __half* __restrict__ h3raw, const float* __restrict__ scsh,
    const float* __restrict__ x,
    const float* __restrict__ mW1, const float* __restrict__ mb1,
    const float* __restrict__ mW2, const float* __restrict__ mb2,
    const float* __restrict__ pW, const float* __restrict__ pb,
    const float* __restrict__ vW, const float* __restrict__ vb,
    float* __restrict__ out, int n) {
  __shared__ float lds[9280];
  float* a1  = lds;           // 64*68 = 4352; GEMM1 input, then GEMM1 output
  float* ctx = lds + 4352;    // 64*8  = 512
  float* w1  = lds + 4864;    // 69*64 = 4416; then w2 (64*64 = 4096)

  int t = threadIdx.x;
  int node0 = blockIdx.x * 64;
  int rows = min(64, n - node0);

#pragma unroll
  for (int i = 0; i < 2; i++) {
    int flat = t + i * 256;           // 64 rows x 8 chunks of 8 halves
    int r = flat >> 3, kc = flat & 7;
    uint4 hv = make_uint4(0, 0, 0, 0);
    if (r < rows) hv = *(const uint4*)(h3raw + (size_t)(node0 + r) * 64 + kc * 8);
    float2 f0 = __half22float2(__builtin_bit_cast(__half2, hv.x));
    float2 f1 = __half22float2(__builtin_bit_cast(__half2, hv.y));
    float2 f2 = __half22float2(__builtin_bit_cast(__half2, hv.z));
    float2 f3 = __half22float2(__builtin_bit_cast(__half2, hv.w));
    const float* sc = &scsh[kc * 8];
    const float* sh = &scsh[64 + kc * 8];
    float4 va, vb2;
    va.x = fmaxf(fmaf(f0.x, sc[0], sh[0]), 0.f);
    va.y = fmaxf(fmaf(f0.y, sc[1], sh[1]), 0.f);
    va.z = fmaxf(fmaf(f1.x, sc[2], sh[2]), 0.f);
    va.w = fmaxf(fmaf(f1.y, sc[3], sh[3]), 0.f);
    vb2.x = fmaxf(fmaf(f2.x, sc[4], sh[4]), 0.f);
    vb2.y = fmaxf(fmaf(f2.y, sc[5], sh[5]), 0.f);
    vb2.z = fmaxf(fmaf(f3.x, sc[6], sh[6]), 0.f);
    vb2.w = fmaxf(fmaf(f3.y, sc[7], sh[7]), 0.f);
    *(float4*)&a1[r * 68 + kc * 8] = va;
    *(float4*)&a1[r * 68 + kc * 8 + 4] = vb2;
  }
  for (int i = t; i < 320; i += 256) {
    int r = i / 5, j = i % 5;
    ctx[r * 8 + j] = (r < rows) ? x[(size_t)(node0 + r) * 16 + 9 + j] : 0.f;
  }
#pragma unroll
  for (int i = 0; i < 5; i++) {
    int flat = t + i * 256;
    if (flat < 1104) *(float4*)&w1[flat * 4] = *(const float4*)&mW1[flat * 4];
  }
  __syncthreads();

  int tc = t & 15, tr = t >> 4;
  int c0 = tc * 4, r0 = tr * 4;

  float acc[4][4] = {};
  for (int k = 0; k < 64; k += 4) {
    float4 av[4], wv[4];
#pragma unroll
    for (int i = 0; i < 4; i++) av[i] = *(const float4*)&a1[(r0 + i) * 68 + k];
#pragma unroll
    for (int j = 0; j < 4; j++) wv[j] = *(const float4*)&w1[(k + j) * 64 + c0];
#pragma unroll
    for (int i = 0; i < 4; i++) {
      const float* ai = (const float*)&av[i];
#pragma unroll
      for (int kk = 0; kk < 4; kk++) {
        const float* wr = (const float*)&wv[kk];
        acc[i][0] = fmaf(ai[kk], wr[0], acc[i][0]);
        acc[i][1] = fmaf(ai[kk], wr[1], acc[i][1]);
        acc[i][2] = fmaf(ai[kk], wr[2], acc[i][2]);
        acc[i][3] = fmaf(ai[kk], wr[3], acc[i][3]);
      }
    }
  }
#pragma unroll
  for (int k = 64; k < 69; k++) {
    float4 wv = *(const float4*)&w1[k * 64 + c0];
    const float* wr = (const float*)&wv;
#pragma unroll
    for (int i = 0; i < 4; i++) {
      float a = ctx[(r0 + i) * 8 + (k - 64)];
      acc[i][0] = fmaf(a, wr[0], acc[i][0]);
      acc[i][1] = fmaf(a, wr[1], acc[i][1]);
      acc[i][2] = fmaf(a, wr[2], acc[i][2]);
      acc[i][3] = fmaf(a, wr[3], acc[i][3]);
    }
  }
  float b1v0 = mb1[c0], b1v1 = mb1[c0 + 1], b1v2 = mb1[c0 + 2], b1v3 = mb1[c0 + 3];
  float4 t1v[4];
#pragma unroll
  for (int i = 0; i < 4; i++) {
    t1v[i].x = fmaxf(acc[i][0] + b1v0, 0.f);
    t1v[i].y = fmaxf(acc[i][1] + b1v1, 0.f);
    t1v[i].z = fmaxf(acc[i][2] + b1v2, 0.f);
    t1v[i].w = fmaxf(acc[i][3] + b1v3, 0.f);
  }
  __syncthreads();  // all GEMM1 reads of a1/w1 done -> regions reusable

  // GEMM1 output in-place over a1; w2 over w1
#pragma unroll
  for (int i = 0; i < 4; i++)
    *(float4*)&a1[(r0 + i) * 68 + c0] = t1v[i];
#pragma unroll
  for (int i = 0; i < 4; i++) {
    int flat = t + i * 256;
    *(float4*)&w1[flat * 4] = *(const float4*)&mW2[flat * 4];
  }
  __syncthreads();

  float acc2[4][4] = {};
  for (int k = 0; k < 64; k += 4) {
    float4 av[4], wv[4];
#pragma unroll
    for (int i = 0; i < 4; i++) av[i] = *(const float4*)&a1[(r0 + i) * 68 + k];
#pragma unroll
    for (int j = 0; j < 4; j++) wv[j] = *(const float4*)&w1[(k + j) * 64 + c0];
#pragma unroll
    for (int i = 0; i < 4; i++) {
      const float* ai = (const float*)&av[i];
#pragma unroll
      for (int kk = 0; kk < 4; kk++) {
        const float* wr = (const float*)&wv[kk];
        acc2[i][0] = fmaf(ai[kk], wr[0], acc2[i][0]);
        acc2[i][1] = fmaf(ai[kk], wr[1], acc2[i][1]);
        acc2[i][2] = fmaf(ai[kk], wr[2], acc2[i][2]);
        acc2[i][3] = fmaf(ai[kk], wr[3], acc2[i][3]);
      }
    }
  }

  float b2v[4], pwv[4], vwv[4];
#pragma unroll
  for (int j = 0; j < 4; j++) {
    b2v[j] = mb2[c0 + j];
    pwv[j] = pW[c0 + j];
    vwv[j] = vW[c0 + j];
  }
  float p[4], v[4];
#pragma unroll
  for (int i = 0; i < 4; i++) {
    float ps = 0.f, vs = 0.f;
#pragma unroll
    for (int j = 0; j < 4; j++) {
      float u = acc2[i][j] + b2v[j];
      ps = fmaf(u, pwv[j], ps);
      vs = fmaf(u, vwv[j], vs);
    }
    p[i] = ps; v[i] = vs;
  }
#pragma unroll
  for (int off = 1; off < 16; off <<= 1) {
#pragma unroll
    for (int i = 0; i < 4; i++) {
      p[i] += __shfl_xor(p[i], off);
      v[i] += __shfl_xor(v[i], off);
    }
  }
  if (tc == 0) {
    float pbs = pb[0], vbs = vb[0];
#pragma unroll
    for (int i = 0; i < 4; i++) {
      int r = r0 + i;
      if (r < rows) {
        out[node0 + r] = p[i] + pbs;
        out[n + node0 + r] = v[i] + vbs;
      }
    }
  }
}

extern "C" void kernel_launch(void* const* d_in, const int* in_sizes, int n_in,
                              void* d_out, int out_size, void* d_ws, size_t ws_size,
                              hipStream_t stream) {
  const float* x = (const float*)d_in[0];
  const int* ei = (const int*)d_in[1];
  const float* W[3]  = {(const float*)d_in[2],  (const float*)d_in[8],  (const float*)d_in[14]};
  const float* AS[3] = {(const float*)d_in[3],  (const float*)d_in[9],  (const float*)d_in[15]};
  const float* AD[3] = {(const float*)d_in[4],  (const float*)d_in[10], (const float*)d_in[16]};
  const float* B[3]  = {(const float*)d_in[5],  (const float*)d_in[11], (const float*)d_in[17]};
  const float* G[3]  = {(const float*)d_in[6],  (const float*)d_in[12], (const float*)d_in[18]};
  const float* BE[3] = {(const float*)d_in[7],  (const float*)d_in[13], (const float*)d_in[19]};
  const float* mW1 = (const float*)d_in[20];
  const float* mb1 = (const float*)d_in[21];
  const float* mW2 = (const float*)d_in[22];
  const float* mb2 = (const float*)d_in[23];
  const float* pW  = (const float*)d_in[24];
  const float* pb  = (const float*)d_in[25];
  const float* vW  = (const float*)d_in[26];
  const float* vb  = (const float*)d_in[27];

  const int N = in_sizes[0] / 16;
  const int E = in_sizes[1] / 2;
  const int* srcp = ei;
  const int* dstp = ei + E;

  // workspace carve-up (~60 MB). bufB region kept at N*64 floats for layout
  // stability; only the first half (N*64 halves) is used now.
  float* bufB  = (float*)d_ws;               // N*64 halves (fp16 activations)
  float* hbuf  = bufB + (size_t)N * 64;      // N*64 half2 region
  float* as_   = hbuf + (size_t)N * 64;      // N*2
  float* ad_   = as_ + (size_t)N * 2;        // N*2
  float* stats = ad_ + (size_t)N * 2;        // NSL*128
  float* scsh  = stats + NSL * 128;          // 128
  __half* wTg  = (__half*)(scsh + 128);      // 23040 halves (3 x [144][KE])
  int* row_ptr = (int*)(wTg + 23040);        // N+1
  int* bcnt    = row_ptr + (N + 1);          // 512
  int* boff    = bcnt + 512;                 // 512
  int* bcur    = boff + 512;                 // 512
  int* col     = bcur + 512;                 // E ints (sorted CSR, src only)
  int2* ebuf   = (int2*)(col + E);           // E int2 (staging)
  __half2* hb  = (__half2*)hbuf;
  __half* bufH = (__half*)bufB;
  const __half* wTgL[3] = {wTg, wTg + 4608, wTg + 13824};

  const int nbk = (N + 255) >> 8;
  const float inv_n = 1.0f / (float)N;

  // ---- W transposes + att precombine (once) + CSR build
  transpose_ws<<<90, 256, 0, stream>>>(W[0], W[1], W[2], AS[0], AD[0],
                                       AS[1], AD[1], AS[2], AD[2], wTg);
  hipMemsetAsync(bcnt, 0, sizeof(int) * 512, stream);
  bucket_hist<<<256, 256, 0, stream>>>(dstp, bcnt, E);
  bucket_scan<<<1, 512, 0, stream>>>(bcnt, boff, bcur, nbk);
  bin_scatter<<<(E + 8191) / 8192, 256, 0, stream>>>(srcp, dstp, bcur, ebuf, E);
  bucket_sort<<<nbk, 256, 0, stream>>>(ebuf, boff, col, row_ptr, E, N, nbk);

  const int tiles = (N + 63) / 64;
  const int agg_blocks = (N + 15) / 16;  // 4 nodes/wave, 4 waves/block

  // ---- 3 GAT layers (BN+ReLU fused into the next consumer via scsh)
  for (int l = 0; l < 3; l++) {
    if (l == 0)
      gat_project_mfma<16, false><<<tiles, 256, 0, stream>>>(x, scsh, wTgL[l],
                                                             hb, as_, ad_, N);
    else
      gat_project_mfma<64, true><<<tiles, 256, 0, stream>>>(bufH, scsh, wTgL[l],
                                                            hb, as_, ad_, N);
    gat_aggregate<<<agg_blocks, 256, 0, stream>>>(hb, as_, ad_, row_ptr, col,
                                                  B[l], bufH, N);
    bn_stats<<<NSL, 256, 0, stream>>>(bufH, stats, N);
    bn_finalize<<<1, 1024, 0, stream>>>(stats, G[l], BE[l], scsh, inv_n);
  }

  // ---- MLP head -> (logits, value); applies layer-3 BN+ReLU to bufH
  mlp_head_tiled<<<tiles, 256, 0, stream>>>(bufH, scsh, x, mW1, mb1, mW2, mb2,
                                            pW, pb, vW, vb, (float*)d_out, N);
}